// Round 13
// baseline (627.804 us; speedup 1.0000x reference)
//
#include <hip/hip_runtime.h>
#include <hip/hip_bf16.h>
#include <math.h>

typedef unsigned short u16;
typedef __attribute__((ext_vector_type(8))) short s8v;
typedef __attribute__((ext_vector_type(4))) short s4v;
typedef __attribute__((ext_vector_type(4))) float f4v;

#define B_   2
#define S_   1024
#define T_   2048
#define H_   2048
#define NH_  16
#define DH_  128
#define R_   64
#define CQ_  1024
#define CKV_ 512
#define DQK_ 192
#define E_   8
#define I_   1024
#define NS_  2

__device__ __forceinline__ float us2f(u16 u){
  unsigned int i = ((unsigned int)u) << 16; float f; __builtin_memcpy(&f, &i, 4); return f;
}
__device__ __forceinline__ u16 f2us(float f){
  unsigned int i; __builtin_memcpy(&i, &f, 4);
  unsigned int r = i + 0x7fffu + ((i >> 16) & 1u);
  return (u16)(r >> 16);
}
__device__ __forceinline__ f4v MFMA_B16(s8v a, s8v b, f4v c){
  return __builtin_amdgcn_mfma_f32_16x16x32_bf16(a, b, c, 0, 0, 0);
}

typedef const __attribute__((address_space(1))) void* gas_ptr;
typedef __attribute__((address_space(3))) void* las_ptr;
__device__ __forceinline__ void gload16(const void* g, void* l){
  __builtin_amdgcn_global_load_lds((gas_ptr)g, (las_ptr)l, 16, 0, 0);
}

// ---------------- rope table ----------------
__global__ void rope_table_kernel(float* __restrict__ cosT, float* __restrict__ sinT){
  int i = blockIdx.x * 256 + threadIdx.x;
  if (i >= S_ * 32) return;
  int s = i >> 5, f = i & 31;
  double inv = exp(-(double)f / 32.0 * log(10000.0));
  double t = (double)s * inv;
  cosT[i] = (float)cos(t);
  sinT[i] = (float)sin(t);
}

// ---------------- transpose + fp32->bf16 convert ----------------
__global__ __launch_bounds__(256) void ttc_kernel(const float* __restrict__ in, u16* __restrict__ outp,
                                                  int Kd, int Nd, size_t zs, int rowoff, int rowmul){
  __shared__ float tile[64][65];
  size_t ibase = (size_t)blockIdx.z * Kd * Nd;
  size_t obase = (size_t)blockIdx.z * zs;
  int k0 = blockIdx.y * 64, n0 = blockIdx.x * 64;
  int tid = threadIdx.x;
  int tx = tid & 15, ty = tid >> 4;
  #pragma unroll
  for (int pp = 0; pp < 4; pp++){
    int kk = pp * 16 + ty;
    f4v v = *(const f4v*)(in + ibase + (size_t)(k0 + kk) * Nd + n0 + tx * 4);
    tile[kk][tx * 4 + 0] = v[0];
    tile[kk][tx * 4 + 1] = v[1];
    tile[kk][tx * 4 + 2] = v[2];
    tile[kk][tx * 4 + 3] = v[3];
  }
  __syncthreads();
  #pragma unroll
  for (int pp = 0; pp < 4; pp++){
    int nn = pp * 16 + ty;
    s4v o;
    #pragma unroll
    for (int j = 0; j < 4; j++) o[j] = (short)f2us(tile[tx * 4 + j][nn]);
    *(s4v*)(outp + obase + (size_t)(rowoff + (n0 + nn) * rowmul) * Kd + k0 + tx * 4) = o;
  }
}

// ---------------- rmsnorm ----------------
__global__ __launch_bounds__(256) void rmsnorm_kernel(const float* __restrict__ in, const float* __restrict__ w,
                                                      u16* __restrict__ outb, float* __restrict__ outf, int D){
  int t = blockIdx.x;
  const float* row = in + (size_t)t * D;
  float ss = 0.f;
  for (int i = threadIdx.x * 4; i < D; i += 1024){
    f4v v = *(const f4v*)(row + i);
    ss += v[0]*v[0] + v[1]*v[1] + v[2]*v[2] + v[3]*v[3];
  }
  #pragma unroll
  for (int m = 1; m < 64; m <<= 1) ss += __shfl_xor(ss, m);
  __shared__ float red[4];
  if ((threadIdx.x & 63) == 0) red[threadIdx.x >> 6] = ss;
  __syncthreads();
  float tot = red[0] + red[1] + red[2] + red[3];
  float r = 1.0f / sqrtf(tot / (float)D + 1e-5f);
  for (int i = threadIdx.x * 4; i < D; i += 1024){
    f4v v = *(const f4v*)(row + i);
    f4v wv = *(const f4v*)(w + i);
    s4v ob;
    f4v of;
    #pragma unroll
    for (int j = 0; j < 4; j++){ of[j] = v[j] * r * wv[j]; ob[j] = (short)f2us(of[j]); }
    *(s4v*)(outb + (size_t)t * D + i) = ob;
    if (outf) *(f4v*)(outf + (size_t)t * D + i) = of;
  }
}

// ---------------- bf16 MFMA GEMM core: 128x128, BK=32, 8 waves (2x4), 3-buffer SINGLE-barrier pipeline ----------------
// OUTMODE: 0 f32, 1 bf16, 2 f32+resid, 4 split bf16/bf16, 5 split3 f32, 6 silu-pair bf16 (resid=roww)
template<int OUTMODE, bool AGATHER>
__device__ __forceinline__ void gemm_core(const u16* __restrict__ A, int lda,
                                          const u16* __restrict__ Bt, int K, int M,
                                          const int* __restrict__ arows,
                                          float* __restrict__ outf0, float* __restrict__ outf1,
                                          float* __restrict__ outf2,
                                          u16* __restrict__ outb0, u16* __restrict__ outb1,
                                          int ldc0, int ldc1, int split, int split2,
                                          const float* __restrict__ resid,
                                          int bm0, int bn0){
  __shared__ u16 As[3][128 * 32];
  __shared__ u16 Bs[3][128 * 32];
  int tid = threadIdx.x;
  int w = tid >> 6, lane = tid & 63;
  int wr = w >> 2, wc = w & 3;
  int g = lane >> 4, l16 = lane & 15;

  f4v acc[4][2];
  #pragma unroll
  for (int m = 0; m < 4; m++)
    #pragma unroll
    for (int n = 0; n < 2; n++) acc[m][n] = (f4v)0.0f;

  int c = tid;
  int row = c >> 2;
  int sc = (c & 3) ^ ((c >> 3) & 3);
  int grow = bm0 + row;
  int ar;
  if (AGATHER) ar = arows[(grow < M) ? grow : 0];
  else         ar = (grow < M) ? grow : 0;
  const u16* asrc = A + (size_t)ar * lda + sc * 8;
  const u16* bsrc = Bt + (size_t)(bn0 + row) * K + sc * 8;
  int dst = (w * 64) * 8;
  int apos = (g ^ ((l16 >> 1) & 3)) * 8;

  int nt = K >> 5;   // >= 2 always (K >= 64)
  // prologue: stage steps 0 and 1
  gload16(asrc, &As[0][dst]);
  gload16(bsrc, &Bs[0][dst]);
  gload16(asrc + 32, &As[1][dst]);
  gload16(bsrc + 32, &Bs[1][dst]);
  asm volatile("s_waitcnt vmcnt(2)" ::: "memory");
  __builtin_amdgcn_s_barrier();
  asm volatile("" ::: "memory");

  int rb = 0;
  for (int t = 0; t < nt; ++t){
    s8v af[4], bf[2];
    #pragma unroll
    for (int m = 0; m < 4; m++) af[m] = *(const s8v*)(&As[rb][(wr * 64 + m * 16 + l16) * 32 + apos]);
    #pragma unroll
    for (int n = 0; n < 2; n++) bf[n] = *(const s8v*)(&Bs[rb][(wc * 32 + n * 16 + l16) * 32 + apos]);
    if (t + 2 < nt){
      int kn = (t + 2) * 32;
      int wb = rb + 2; if (wb >= 3) wb -= 3;
      gload16(asrc + kn, &As[wb][dst]);
      gload16(bsrc + kn, &Bs[wb][dst]);
    }
    __builtin_amdgcn_s_setprio(1);
    #pragma unroll
    for (int m = 0; m < 4; m++)
      #pragma unroll
      for (int n = 0; n < 2; n++)
        acc[m][n] = MFMA_B16(af[m], bf[n], acc[m][n]);
    __builtin_amdgcn_s_setprio(0);
    if (t + 2 < nt){
      asm volatile("s_waitcnt vmcnt(2)" ::: "memory");
    } else {
      asm volatile("s_waitcnt vmcnt(0)" ::: "memory");
    }
    __builtin_amdgcn_s_barrier();
    asm volatile("" ::: "memory");
    rb = (rb == 2) ? 0 : rb + 1;
  }

  #pragma unroll
  for (int m = 0; m < 4; m++)
    #pragma unroll
    for (int n = 0; n < 2; n++){
      int ccol = bn0 + wc * 32 + n * 16 + l16;
      #pragma unroll
      for (int j = 0; j < 4; j++){
        int r = wr * 64 + m * 16 + g * 4 + j;
        int gr = bm0 + r;
        float v = acc[m][n][j];
        if (OUTMODE == 6){
          float other = __shfl_xor(v, 1);
          if (gr < M && (lane & 1) == 0){
            float wgt = resid[gr];
            float gm = v / (1.f + __expf(-v));
            outb0[(size_t)gr * ldc0 + (ccol >> 1)] = f2us(gm * other * wgt);
          }
          continue;
        }
        if (gr >= M) continue;
        if (OUTMODE == 0){
          outf0[(size_t)gr * ldc0 + ccol] = v;
        } else if (OUTMODE == 1){
          outb0[(size_t)gr * ldc0 + ccol] = f2us(v);
        } else if (OUTMODE == 2){
          outf0[(size_t)gr * ldc0 + ccol] = v + resid[(size_t)gr * ldc0 + ccol];
        } else if (OUTMODE == 4){
          if (ccol < split) outb0[(size_t)gr * ldc0 + ccol] = f2us(v);
          else              outb1[(size_t)gr * ldc1 + (ccol - split)] = f2us(v);
        } else { // 5
          if (ccol < split)       outf0[(size_t)gr * ldc0 + ccol] = v;
          else if (ccol < split2) outf1[(size_t)gr * ldc1 + (ccol - split)] = v;
          else if (ccol < split2 + 64) outf2[(size_t)gr * 64 + (ccol - split2)] = v;
        }
      }
    }
}

// ---------------- dense core: 64x128 tile, BK=32, 4 waves (2x2), 24KB LDS, counted-vmcnt (r12 config) ----------------
template<int OUTMODE>
__device__ __forceinline__ void gemm_core64(const u16* __restrict__ A, int lda,
                                            const u16* __restrict__ Bt, int K, int M,
                                            float* __restrict__ outf0, float* __restrict__ outf1,
                                            float* __restrict__ outf2,
                                            u16* __restrict__ outb0, u16* __restrict__ outb1,
                                            int ldc0, int ldc1, int split, int split2,
                                            const float* __restrict__ resid,
                                            int bm0, int bn0){
  __shared__ u16 As[2][64 * 32];
  __shared__ u16 Bs[2][128 * 32];
  int tid = threadIdx.x;
  int w = tid >> 6, lane = tid & 63;
  int wr = w >> 1, wc = w & 1;
  int g = lane >> 4, l16 = lane & 15;

  f4v acc[2][4];
  #pragma unroll
  for (int m = 0; m < 2; m++)
    #pragma unroll
    for (int n = 0; n < 4; n++) acc[m][n] = (f4v)0.0f;

  int ca = tid;
  int rowa = ca >> 2;
  int sca = (ca & 3) ^ ((ca >> 3) & 3);
  const u16* asrc = A + (size_t)(bm0 + rowa) * lda + sca * 8;
  int dsta = (w * 64) * 8;
  const u16* bsrc[2];
  int dstb[2];
  #pragma unroll
  for (int p = 0; p < 2; p++){
    int c = tid + p * 256;
    int rowb = c >> 2;
    int scb = (c & 3) ^ ((c >> 3) & 3);
    bsrc[p] = Bt + (size_t)(bn0 + rowb) * K + scb * 8;
    dstb[p] = (p * 256 + w * 64) * 8;
  }
  int apos = (g ^ ((l16 >> 1) & 3)) * 8;

  int nt = K >> 5;
  gload16(asrc, &As[0][dsta]);
  #pragma unroll
  for (int p = 0; p < 2; p++) gload16(bsrc[p], &Bs[0][dstb[p]]);

  int cur = 0;
  for (int t = 0; t < nt; ++t){
    if (t + 1 < nt){
      int kn = (t + 1) * 32;
      gload16(asrc + kn, &As[cur ^ 1][dsta]);
      #pragma unroll
      for (int p = 0; p < 2; p++) gload16(bsrc[p] + kn, &Bs[cur ^ 1][dstb[p]]);
      asm volatile("s_waitcnt vmcnt(3)" ::: "memory");
    } else {
      asm volatile("s_waitcnt vmcnt(0)" ::: "memory");
    }
    __builtin_amdgcn_s_barrier();
    asm volatile("" ::: "memory");
    s8v af[2], bf[4];
    #pragma unroll
    for (int m = 0; m < 2; m++) af[m] = *(const s8v*)(&As[cur][(wr * 32 + m * 16 + l16) * 32 + apos]);
    #pragma unroll
    for (int n = 0; n < 4; n++) bf[n] = *(const s8v*)(&Bs[cur][(wc * 64 + n * 16 + l16) * 32 + apos]);
    __builtin_amdgcn_s_setprio(1);
    #pragma unroll
    for (int m = 0; m < 2; m++)
      #pragma unroll
      for (int n = 0; n < 4; n++)
        acc[m][n] = MFMA_B16(af[m], bf[n], acc[m][n]);
    __builtin_amdgcn_s_setprio(0);
    asm volatile("" ::: "memory");
    __builtin_amdgcn_s_barrier();
    cur ^= 1;
  }

  #pragma unroll
  for (int m = 0; m < 2; m++)
    #pragma unroll
    for (int n = 0; n < 4; n++){
      int ccol = bn0 + wc * 64 + n * 16 + l16;
      #pragma unroll
      for (int j = 0; j < 4; j++){
        int r = wr * 32 + m * 16 + g * 4 + j;
        int gr = bm0 + r;
        if (gr >= M) continue;
        float v = acc[m][n][j];
        if (OUTMODE == 0){
          outf0[(size_t)gr * ldc0 + ccol] = v;
        } else if (OUTMODE == 1){
          outb0[(size_t)gr * ldc0 + ccol] = f2us(v);
        } else if (OUTMODE == 2){
          outf0[(size_t)gr * ldc0 + ccol] = v + resid[(size_t)gr * ldc0 + ccol];
        } else if (OUTMODE == 4){
          if (ccol < split) outb0[(size_t)gr * ldc0 + ccol] = f2us(v);
          else              outb1[(size_t)gr * ldc1 + (ccol - split)] = f2us(v);
        } else { // 5
          if (ccol < split)       outf0[(size_t)gr * ldc0 + ccol] = v;
          else if (ccol < split2) outf1[(size_t)gr * ldc1 + (ccol - split)] = v;
          else if (ccol < split2 + 64) outf2[(size_t)gr * 64 + (ccol - split2)] = v;
        }
      }
    }
}

template<int OUTMODE>
__global__ __launch_bounds__(256) void gemm_kernel64(const u16* __restrict__ A, int lda,
                                                     const u16* __restrict__ Bt, int K, int M,
                                                     float* __restrict__ outf0, float* __restrict__ outf1,
                                                     float* __restrict__ outf2,
                                                     u16* __restrict__ outb0, u16* __restrict__ outb1,
                                                     int ldc0, int ldc1, int split, int split2,
                                                     const float* __restrict__ resid){
  int gx = gridDim.x;
  int nwg = gx * gridDim.y;
  int orig = blockIdx.y * gx + blockIdx.x;
  int wg = orig;
  if ((nwg & 7) == 0) wg = (orig & 7) * (nwg >> 3) + (orig >> 3);
  int bx = wg % gx, by = wg / gx;
  gemm_core64<OUTMODE>(A, lda, Bt, K, M,
                       outf0, outf1, outf2, outb0, outb1, ldc0, ldc1, split, split2, resid,
                       by * 64, bx * 128);
}

// ---------------- build qcat/kcat [B][NH][S][192], 8 elems/thread ----------------
__global__ __launch_bounds__(256) void build_qcat_kernel(const u16* __restrict__ qbuf, const u16* __restrict__ qrb,
                                                         const float* __restrict__ cosT, const float* __restrict__ sinT,
                                                         u16* __restrict__ qcat){
  size_t i8 = ((size_t)blockIdx.x * 256 + threadIdx.x) * 8;
  const size_t total = (size_t)B_ * NH_ * S_ * DQK_;
  if (i8 >= total) return;
  int d = (int)(i8 % DQK_); size_t rem = i8 / DQK_;
  int s = (int)(rem % S_); rem /= S_;
  int h = (int)(rem % NH_); int b = (int)(rem / NH_);
  int t = b * S_ + s;
  s8v o;
  if (d < DH_){
    o = *(const s8v*)(qbuf + (size_t)t * H_ + h * DH_ + d);
  } else {
    int r0 = d - DH_;
    int rr0 = r0 & 31;
    const u16* qp = qrb + (size_t)t * (NH_ * R_) + h * R_;
    #pragma unroll
    for (int j = 0; j < 8; j++){
      float c = cosT[s * 32 + rr0 + j], sn = sinT[s * 32 + rr0 + j];
      float lo = us2f(qp[rr0 + j]), hi = us2f(qp[rr0 + 32 + j]);
      float val = (r0 < 32) ? (lo * c - hi * sn) : (hi * c + lo * sn);
      o[j] = (short)f2us(val);
    }
  }
  *(s8v*)(qcat + i8) = o;
}

__global__ __launch_bounds__(256) void build_kcat_kernel(const u16* __restrict__ kbuf, const float* __restrict__ krb,
                                                         const float* __restrict__ cosT, const float* __restrict__ sinT,
                                                         u16* __restrict__ kcat){
  size_t i8 = ((size_t)blockIdx.x * 256 + threadIdx.x) * 8;
  const size_t total = (size_t)B_ * NH_ * S_ * DQK_;
  if (i8 >= total) return;
  int d = (int)(i8 % DQK_); size_t rem = i8 / DQK_;
  int s = (int)(rem % S_); rem /= S_;
  int h = (int)(rem % NH_); int b = (int)(rem / NH_);
  int t = b * S_ + s;
  s8v o;
  if (d < DH_){
    o = *(const s8v*)(kbuf + (size_t)t * H_ + h * DH_ + d);
  } else {
    int r0 = d - DH_;
    int rr0 = r0 & 31;
    const float* kp = krb + (size_t)t * R_;
    #pragma unroll
    for (int j = 0; j < 8; j++){
      float c = cosT[s * 32 + rr0 + j], sn = sinT[s * 32 + rr0 + j];
      float lo = kp[rr0 + j], hi = kp[rr0 + 32 + j];
      float val = (r0 < 32) ? (lo * c - hi * sn) : (hi * c + lo * sn);
      o[j] = (short)f2us(val);
    }
  }
  *(s8v*)(kcat + i8) = o;
}

// ---------------- vT[b][h][d][s] = v[b][s][h*128+d] ----------------
__global__ __launch_bounds__(256) void build_vT_kernel(const u16* __restrict__ vbuf, u16* __restrict__ vT){
  __shared__ u16 tile[32][33];
  int bh = blockIdx.z; int b = bh >> 4, h = bh & 15;
  int s0 = blockIdx.x * 32, d0 = blockIdx.y * 32;
  int tx = threadIdx.x & 31, ty = threadIdx.x >> 5;
  for (int i = ty; i < 32; i += 8)
    tile[i][tx] = vbuf[(size_t)(b * S_ + s0 + i) * H_ + h * DH_ + d0 + tx];
  __syncthreads();
  for (int i = ty; i < 32; i += 8)
    vT[((size_t)bh * DH_ + d0 + i) * S_ + s0 + tx] = tile[tx][i];
}

// ---------------- flash attention: 4 waves/block, QBLK=64, KVBLK=64 ----------------
__global__ __launch_bounds__(256) void attn_kernel(const u16* __restrict__ qcat, const u16* __restrict__ kcat,
                                                   const u16* __restrict__ vT, u16* __restrict__ aout){
  __shared__ u16 Ks[64 * 192];
  __shared__ u16 Vs[128 * 64];
  __shared__ u16 Ps[4][16][72];

  int qb = (int)(gridDim.x - 1) - (int)blockIdx.x;
  int h = blockIdx.y, b = blockIdx.z;
  int bh = b * NH_ + h;
  int tid = threadIdx.x;
  int w = tid >> 6, lane = tid & 63;
  int g = lane >> 4, l16 = lane & 15;
  int qrow0 = qb * 64 + w * 16;
  int qglob = qrow0 + l16;
  int qmax = qrow0 + 15;
  const float scale = 0.07216878364870323f;

  s8v qf[6];
  const u16* qrow = qcat + ((size_t)bh * S_ + qglob) * DQK_;
  #pragma unroll
  for (int c = 0; c < 6; c++) qf[c] = *(const s8v*)(qrow + c * 32 + g * 8);

  int koff[6];
  #pragma unroll
  for (int i = 0; i < 6; i++){
    int ci = tid + i * 256;
    int row = ci / 24, cp = ci - row * 24;
    koff[i] = row * 192 + ((cp ^ (row & 7)) * 8);
  }
  int voff[4];
  #pragma unroll
  for (int i = 0; i < 4; i++){
    int ci = tid + i * 256;
    int d = ci >> 3, cp = ci & 7;
    voff[i] = d * S_ + ((cp ^ (d & 7)) * 8);
  }

  const u16* kbase_g = kcat + (size_t)bh * S_ * DQK_;
  const u16* vbase_g = vT + (size_t)bh * DH_ * S_;

  f4v o[8];
  #pragma unroll
  for (int i = 0; i < 8; i++) o[i] = (f4v)0.0f;
  float mrow = -1e30f, lrow = 0.0f;

  int nkt = qb + 1;
  for (int it = 0; it < nkt; it++){
    int kv0 = it * 64;
    const u16* ksrc = kbase_g + (size_t)kv0 * DQK_;
    #pragma unroll
    for (int i = 0; i < 6; i++) gload16(ksrc + koff[i], &Ks[(i * 256 + w * 64) * 8]);
    #pragma unroll
    for (int i = 0; i < 4; i++) gload16(vbase_g + kv0 + voff[i], &Vs[(i * 256 + w * 64) * 8]);
    __syncthreads();

    f4v st[4];
    #pragma unroll
    for (int kf = 0; kf < 4; kf++){
      f4v a = (f4v)0.0f;
      if (kv0 + kf * 16 <= qmax){
        int row = kf * 16 + l16;
        int sw = (row & 7);
        #pragma unroll
        for (int c = 0; c < 6; c++){
          s8v kfr = *(const s8v*)(&Ks[row * 192 + (((c * 4 + g) ^ sw) * 8)]);
          a = MFMA_B16(kfr, qf[c], a);
        }
      }
      st[kf] = a;
    }

    float sv[16];
    #pragma unroll
    for (int kf = 0; kf < 4; kf++)
      #pragma unroll
      for (int j = 0; j < 4; j++){
        int kk = kv0 + kf * 16 + g * 4 + j;
        sv[kf * 4 + j] = (kk <= qglob) ? st[kf][j] * scale : -1e30f;
      }

    float mt = sv[0];
    #pragma unroll
    for (int i = 1; i < 16; i++) mt = fmaxf(mt, sv[i]);
    mt = fmaxf(mt, __shfl_xor(mt, 16));
    mt = fmaxf(mt, __shfl_xor(mt, 32));
    float mnew = fmaxf(mrow, mt);
    float corr = __expf(mrow - mnew);
    float ps = 0.f;
    u16 pb[16];
    #pragma unroll
    for (int i = 0; i < 16; i++){ float pv = __expf(sv[i] - mnew); ps += pv; pb[i] = f2us(pv); }
    ps += __shfl_xor(ps, 16); ps += __shfl_xor(ps, 32);
    lrow = lrow * corr + ps;
    mrow = mnew;
    #pragma unroll
    for (int i = 0; i < 8; i++) o[i] *= corr;

    #pragma unroll
    for (int kf = 0; kf < 4; kf++){
      s4v pw;
      #pragma unroll
      for (int j = 0; j < 4; j++) pw[j] = (short)pb[kf * 4 + j];
      *(s4v*)(&Ps[w][l16][kf * 16 + g * 4]) = pw;
    }

    #pragma unroll
    for (int ks = 0; ks < 2; ks++){
      if (kv0 + ks * 32 <= qmax){
        s4v plo = *(const s4v*)(&Ps[w][l16][ks * 32 + g * 8]);
        s4v phi = *(const s4v*)(&Ps[w][l16][ks * 32 + g * 8 + 4]);
        s8v pf;
        pf[0] = plo[0]; pf[1] = plo[1]; pf[2] = plo[2]; pf[3] = plo[3];
        pf[4] = phi[0]; pf[5] = phi[1]; pf[6] = phi[2]; pf[7] = phi[3];
        #pragma unroll
        for (int dt = 0; dt < 8; dt++){
          int d = dt * 16 + l16;
          s8v vf = *(const s8v*)(&Vs[d * 64 + ((((ks * 4 + g) ^ (d & 7))) * 8)]);
          o[dt] = MFMA_B16(vf, pf, o[dt]);
        }
      }
    }
    __syncthreads();
  }

  float inv = 1.0f / lrow;
  int trow = b * S_ + qglob;
  #pragma unroll
  for (int dt = 0; dt < 8; dt++){
    s4v wv;
    #pragma unroll
    for (int j = 0; j < 4; j++) wv[j] = (short)f2us(o[dt][j] * inv);
    *(s4v*)(aout + (size_t)trow * H_ + h * DH_ + dt * 16 + g * 4) = wv;
  }
}

// ---------------- MoE routing ----------------
__global__ __launch_bounds__(64) void route_kernel(const float* __restrict__ h2f, const float* __restrict__ cent,
                                                   const float* __restrict__ bias,
                                                   int* __restrict__ eidx, float* __restrict__ ew,
                                                   int* __restrict__ counts){
  int t = blockIdx.x, lane = threadIdx.x;
  float acc[E_];
  #pragma unroll
  for (int e = 0; e < E_; e++) acc[e] = 0.f;
  for (int k = lane; k < H_; k += 64){
    float xv = h2f[(size_t)t * H_ + k];
    #pragma unroll
    for (int e = 0; e < E_; e++) acc[e] += xv * cent[(size_t)e * H_ + k];
  }
  #pragma unroll
  for (int m = 1; m < 64; m <<= 1)
    #pragma unroll
    for (int e = 0; e < E_; e++) acc[e] += __shfl_xor(acc[e], m);
  float s[E_], sb[E_];
  #pragma unroll
  for (int e = 0; e < E_; e++){ s[e] = 1.f / (1.f + expf(-acc[e])); sb[e] = s[e] + bias[e]; }
  int i0 = 0;
  #pragma unroll
  for (int e = 1; e < E_; e++) if (sb[e] > sb[i0]) i0 = e;
  int i1 = -1;
  #pragma unroll
  for (int e = 0; e < E_; e++) if (e != i0 && (i1 < 0 || sb[e] > sb[i1])) i1 = e;
  float w0 = s[i0], w1 = s[i1], nrm = w0 + w1;
  w0 /= nrm; w1 /= nrm;
  if (lane == 0){
    eidx[t * 2] = i0; eidx[t * 2 + 1] = i1;
    ew[t * 2] = w0; ew[t * 2 + 1] = w1;
    atomicAdd(&counts[i0], 1); atomicAdd(&counts[i1], 1);
  }
}

__global__ void scan_kernel(int* __restrict__ meta){
  if (threadIdx.x == 0 && blockIdx.x == 0){
    int off = 0;
    for (int e = 0; e < E_; e++){ meta[16 + e] = off; meta[32 + e] = meta[e]; off += meta[e]; }
    meta[16 + 8] = 4096; meta[32 + 8] = T_;
    meta[16 + 9] = 4096 + T_; meta[32 + 9] = T_;
  }
}

__global__ void fill_kernel(const int* __restrict__ eidx, const float* __restrict__ ew,
                            int* __restrict__ meta, int* __restrict__ rowlist, float* __restrict__ roww,
                            int* __restrict__ slotidx){
  int t = blockIdx.x * 256 + threadIdx.x;
  if (t >= T_) return;
  for (int j = 0; j < 2; j++){
    int e = eidx[t * 2 + j];
    int p = atomicAdd(&meta[8 + e], 1);
    int slot = meta[16 + e] + p;
    rowlist[slot] = t; roww[slot] = ew[t * 2 + j];
    slotidx[t * 2 + j] = slot;
  }
}

__global__ void init_shared_kernel(int* __restrict__ rowlist, float* __restrict__ roww){
  int i = blockIdx.x * 256 + threadIdx.x;
  if (i >= 2 * T_) return;
  rowlist[4096 + i] = i & (T_ - 1);
  roww[4096 + i] = 0.1f;
}

// ---------------- MoE GEMM wrappers ----------------
// w13T: per expert [2048 rows][K=2048]; row 2j = w1 col j, row 2j+1 = w3 col j (interleaved)
__global__ __launch_bounds__(512) void moe_gemm13_kernel(const u16* __restrict__ h2b,
    const u16* __restrict__ w13T, const u16* __restrict__ w13sT,
    const int* __restrict__ rowlist, const int* __restrict__ listoff, const int* __restrict__ cnt2,
    const float* __restrict__ roww, u16* __restrict__ ub){
  int e = blockIdx.z;
  int cnt = cnt2[e];
  if ((int)(blockIdx.y * 128) >= cnt) return;
  const u16* Bt = (e < 8) ? w13T + (size_t)e * 2048 * H_ : w13sT + (size_t)(e - 8) * 2048 * H_;
  int loff = listoff[e];
  gemm_core<6, true>(h2b, H_, Bt, H_, cnt, rowlist + loff,
                     nullptr, nullptr, nullptr, ub + (size_t)loff * I_, nullptr,
                     I_, 0, 0, 0, roww + loff,
                     blockIdx.y * 128, blockIdx.x * 128);
}

__global__ __launch_bounds__(512) void moe_gemm2_kernel(const u16* __restrict__ ub,
    const u16* __restrict__ w2T, const u16* __restrict__ w2sT,
    const int* __restrict__ listoff, const int* __restrict__ cnt2,
    u16* __restrict__ o2){
  int e = blockIdx.z;
  int cnt = cnt2[e];
  if ((int)(blockIdx.y * 128) >= cnt) return;
  const u16* Bt = (e < 8) ? w2T + (size_t)e * H_ * I_ : w2sT + (size_t)(e - 8) * H_ * I_;
  int loff = listoff[e];
  gemm_core<1, false>(ub + (size_t)loff * I_, I_, Bt, I_, cnt, nullptr,
                      nullptr, nullptr, nullptr, o2 + (size_t)loff * H_, nullptr,
                      H_, 0, 0, 0, nullptr,
                      blockIdx.y * 128, blockIdx.x * 128);
}

__global__ __launch_bounds__(256) void combine_kernel(const float* __restrict__ x1, const u16* __restrict__ o2,
                                                      const int* __restrict__ slotidx, float* __restrict__ out){
  int t = blockIdx.x;
  int s0 = slotidx[2 * t], s1 = slotidx[2 * t + 1];
  const u16* r0 = o2 + (size_t)s0 * H_;
  const u16* r1 = o2 + (size_t)s1 * H_;
  const u16* r2 = o2 + (size_t)(4096 + t) * H_;
  const u16* r3 = o2 + (size_t)(4096 + T_ + t) * H_;
  const float* rx = x1 + (size_t)t * H_;
  float* ro = out + (size_t)t * H_;
  int c = threadIdx.x * 8;
  s8v v0 = *(const s8v*)(r0 + c);
  s8v v1 = *(const s8v*)(r1 + c);
  s8v v2 = *(const s8v*)(r2 + c);
  s8v v3 = *(const s8v*)(r3 + c);
  #pragma unroll
  for (int j = 0; j < 8; j++){
    ro[c + j] = rx[c + j] + us2f((u16)v0[j]) + us2f((u16)v1[j]) + us2f((u16)v2[j]) + us2f((u16)v3[j]);
  }
}

// ============================================================
extern "C" void kernel_launch(void* const* d_in, const int* in_sizes, int n_in,
                              void* d_out, int out_size, void* d_ws, size_t ws_size,
                              hipStream_t stream){
  const float* x    = (const float*)d_in[0];
  const float* anw  = (const float*)d_in[1];
  const float* fnw  = (const float*)d_in[2];
  const float* Wdq  = (const float*)d_in[3];
  const float* qnw  = (const float*)d_in[4];
  const float* Wuq  = (const float*)d_in[5];
  const float* Wqr  = (const float*)d_in[6];
  const float* Wdkv = (const float*)d_in[7];
  const float* kvnw = (const float*)d_in[8];
  const float* Wuk  = (const float*)d_in[9];
  const float* Wuv  = (const float*)d_in[10];
  const float* Wkr  = (const float*)d_in[11];
  const float* Wo   = (const float*)d_in[12];
  const float* cent = (const float*)d_in[13];
  const float* ebias= (const float*)d_in[14];
  const float* w1   = (const float*)d_in[15];
  const float* w3   = (const float*)d_in[16];
  const float* w2   = (const float*)d_in[17];
  const float* w1s  = (const float*)d_in[18];
  const float* w3s  = (const float*)d_in[19];
  const float* w2s  = (const float*)d_in[20];
  float* out = (float*)d_out;

  char* p = (char*)d_ws;
  auto alloc = [&](size_t bytes)->void*{
    void* r = (void*)p; p += (bytes + 255) & ~(size_t)255; return r;
  };

  // ---- persistent region ----
  float* cosT = (float*)alloc((size_t)S_ * 32 * 4);
  float* sinT = (float*)alloc((size_t)S_ * 32 * 4);
  u16* WdqkvT = (u16*)alloc((size_t)1664 * H_ * 2);   // rows: 0-1023 Wdq^T, 1024-1535 Wdkv^T, 1536-1599 Wkr^T, 1600-1663 zero
  u16* WuqrT  = (u16*)alloc((size_t)3072 * CQ_ * 2);
  u16* WukvT  = (u16*)alloc((size_t)4096 * CKV_ * 2);
  u16* WoT   = (u16*)alloc((size_t)H_ * H_ * 2);
  u16* w13T  = (u16*)alloc((size_t)E_ * 2048 * H_ * 2);
  u16* w2T   = (u16*)alloc((size_t)E_ * H_ * I_ * 2);
  u16* w13sT = (u16*)alloc((size_t)NS_ * 2048 * H_ * 2);
  u16* w2sT  = (u16*)alloc((size_t)NS_ * H_ * I_ * 2);
  float* x1  = (float*)alloc((size_t)T_ * H_ * 4);
  float* h2f = (float*)alloc((size_t)T_ * H_ * 4);
  u16* h2b   = (u16*)alloc((size_t)T_ * H_ * 2);
  int* meta  = (int*)alloc(64 * 4);
  int* eidx  = (int*)alloc((size_t)T_ * 2 * 4);
  float* ew  = (float*)alloc((size_t)T_ * 2 * 4);
  int* rowlist = (int*)alloc(8192 * 4);
  float* roww  = (float*)alloc(8192 * 4);
  int* slotidx = (int*)alloc((size_t)T_ * 2 * 4);

  // ---- phase-overlapped region ----
  char* mark = p;
  u16* hn    = (u16*)alloc((size_t)T_ * H_ * 2);
  float* tq  = (float*)alloc((size_t)T_ * CQ_ * 4);
  u16* cq    = (u16*)alloc((size_t)T_ * CQ_ * 2);
  u16* qbuf  = (u16*)alloc((size_t)T_ * H_ * 2);
  u16* qrb   = (u16*)alloc((size_t)T_ * NH_ * R_ * 2);
  float* tkv = (float*)alloc((size_t)T_ * CKV_ * 4);
  u16* ckv   = (u16*)alloc((size_t)T_ * CKV_ * 2);
  u16* kbuf  = (u16*)alloc((size_t)T_ * H_ * 2);
  u16* vbuf  = (u16*)alloc((size_t)T_ * H_ * 2);
  float* krb = (float*)alloc((size_t)T_ * R_ * 4);
  u16* qcat  = (u16*)alloc((size_t)B_ * NH_ * S_ * DQK_ * 2);
  u16* kcat  = (u16*)alloc((size_t)B_ * NH_ * S_ * DQK_ * 2);
  u16* vT    = (u16*)alloc((size_t)B_ * NH_ * DH_ * S_ * 2);
  u16* aout  = (u16*)alloc((size_t)T_ * H_ * 2);

  p = mark;
  u16* ub  = (u16*)alloc((size_t)8192 * I_ * 2);
  u16* o2  = (u16*)alloc((size_t)8192 * H_ * 2);

  dim3 b256(256), b64(64), b512(512);

  hipMemsetAsync(meta, 0, 64 * 4, stream);
  hipMemsetAsync(WdqkvT + (size_t)1600 * H_, 0, (size_t)64 * H_ * 2, stream);

  rope_table_kernel<<<dim3((S_ * 32 + 255) / 256), b256, 0, stream>>>(cosT, sinT);

  ttc_kernel<<<dim3(CQ_ / 64, H_ / 64, 1),  b256, 0, stream>>>(Wdq,  WdqkvT, H_,  CQ_, 0, 0, 1);
  ttc_kernel<<<dim3(CKV_ / 64, H_ / 64, 1), b256, 0, stream>>>(Wdkv, WdqkvT, H_,  CKV_, 0, 1024, 1);
  ttc_kernel<<<dim3(1, H_ / 64, 1),         b256, 0, stream>>>(Wkr,  WdqkvT, H_,  R_, 0, 1536, 1);
  ttc_kernel<<<dim3(H_ / 64, CQ_ / 64, 1),  b256, 0, stream>>>(Wuq,  WuqrT,  CQ_, H_, 0, 0, 1);
  ttc_kernel<<<dim3(1024 / 64, CQ_ / 64, 1), b256, 0, stream>>>(Wqr, WuqrT,  CQ_, 1024, 0, 2048, 1);
  ttc_kernel<<<dim3(H_ / 64, CKV_ / 64, 1), b256, 0, stream>>>(Wuk,  WukvT,  CKV_, H_, 0, 0, 1);
  ttc_kernel<<<dim3(H_ / 64, CKV_ / 64, 1), b256, 0, stream>>>(Wuv,  WukvT,  CKV_, H_, 0, 2048, 1);
  ttc_kernel<<<dim3(H_ / 64, H_ / 64, 1),   b256, 0, stream>>>(Wo,   WoT,    H_,  H_, 0, 0, 1);
  ttc_kernel<<<dim3(I_ / 64, H_ / 64, E_),  b256, 0, stream>>>(w1,  w13T, H_, I_, (size_t)2048 * H_, 0, 2);
  ttc_kernel<<<dim3(I_ / 64, H_ / 64, E_),  b256, 0, stream>>>(w3,  w13T, H_, I_, (size_t)2048 * H_, 1, 2);
  ttc_kernel<<<dim3(H_ / 64, I_ / 64, E_),  b256, 0, stream>>>(w2,  w2T,  I_, H_, (size_t)H_ * I_, 0, 1);
  ttc_kernel<<<dim3(I_ / 64, H_ / 64, NS_), b256, 0, stream>>>(w1s, w13sT, H_, I_, (size_t)2048 * H_, 0, 2);
  ttc_kernel<<<dim3(I_ / 64, H_ / 64, NS_), b256, 0, stream>>>(w3s, w13sT, H_, I_, (size_t)2048 * H_, 1, 2);
  ttc_kernel<<<dim3(H_ / 64, I_ / 64, NS_), b256, 0, stream>>>(w2s, w2sT, I_, H_, (size_t)H_ * I_, 0, 1);

  rmsnorm_kernel<<<T_, b256, 0, stream>>>(x, anw, hn, nullptr, H_);

  // fused dq+dkv+kr: N=1664, splits 1024/1536 -> tq, tkv, krb(raw)
  gemm_kernel64<5><<<dim3(1664 / 128, T_ / 64), b256, 0, stream>>>(hn, H_, WdqkvT, H_, T_,
      tq, tkv, krb, nullptr, nullptr, CQ_, CKV_, 1024, 1536, nullptr);
  rmsnorm_kernel<<<T_, b256, 0, stream>>>(tq, qnw, cq, nullptr, CQ_);
  rmsnorm_kernel<<<T_, b256, 0, stream>>>(tkv, kvnw, ckv, nullptr, CKV_);
  gemm_kernel64<4><<<dim3(3072 / 128, T_ / 64), b256, 0, stream>>>(cq, CQ_, WuqrT, CQ_, T_,
      nullptr, nullptr, nullptr, qbuf, qrb, H_, NH_ * R_, 2048, 0, nullptr);
  gemm_kernel64<4><<<dim3(4096 / 128, T_ / 64), b256, 0, stream>>>(ckv, CKV_, WukvT, CKV_, T_,
      nullptr, nullptr, nullptr, kbuf, vbuf, H_, H_, 2048, 0, nullptr);

  size_t qct = (size_t)B_ * NH_ * S_ * DQK_;
  build_qcat_kernel<<<dim3((qct / 8 + 255) / 256), b256, 0, stream>>>(qbuf, qrb, cosT, sinT, qcat);
  build_kcat_kernel<<<dim3((qct / 8 + 255) / 256), b256, 0, stream>>>(kbuf, krb, cosT, sinT, kcat);
  build_vT_kernel<<<dim3(S_ / 32, DH_ / 32, B_ * NH_), b256, 0, stream>>>(vbuf, vT);

  attn_kernel<<<dim3(S_ / 64, NH_, B_), b256, 0, stream>>>(qcat, kcat, vT, aout);

  gemm_kernel64<2><<<dim3(H_ / 128, T_ / 64), b256, 0, stream>>>(aout, H_, WoT, H_, T_,
      x1, nullptr, nullptr, nullptr, nullptr, H_, 0, 0, 0, x);

  rmsnorm_kernel<<<T_, b256, 0, stream>>>(x1, fnw, h2b, h2f, H_);
  route_kernel<<<T_, b64, 0, stream>>>(h2f, cent, ebias, eidx, ew, meta);
  scan_kernel<<<dim3(1), b64, 0, stream>>>(meta);
  fill_kernel<<<dim3((T_ + 255) / 256), b256, 0, stream>>>(eidx, ew, meta, rowlist, roww, slotidx);
  init_shared_kernel<<<dim3((2 * T_ + 255) / 256), b256, 0, stream>>>(rowlist, roww);

  moe_gemm13_kernel<<<dim3(2048 / 128, 16, 10), b512, 0, stream>>>(h2b, w13T, w13sT,
      rowlist, meta + 16, meta + 32, roww, ub);
  moe_gemm2_kernel<<<dim3(H_ / 128, 16, 10), b512, 0, stream>>>(ub, w2T, w2sT,
      meta + 16, meta + 32, o2);

  combine_kernel<<<T_, b256, 0, stream>>>(x1, o2, slotidx, out);
}

// Round 14
// 602.642 us; speedup vs baseline: 1.0418x; 1.0418x over previous
//
#include <hip/hip_runtime.h>
#include <hip/hip_bf16.h>
#include <math.h>

typedef unsigned short u16;
typedef __attribute__((ext_vector_type(8))) short s8v;
typedef __attribute__((ext_vector_type(4))) short s4v;
typedef __attribute__((ext_vector_type(4))) float f4v;

#define B_   2
#define S_   1024
#define T_   2048
#define H_   2048
#define NH_  16
#define DH_  128
#define R_   64
#define CQ_  1024
#define CKV_ 512
#define DQK_ 192
#define E_   8
#define I_   1024
#define NS_  2

__device__ __forceinline__ float us2f(u16 u){
  unsigned int i = ((unsigned int)u) << 16; float f; __builtin_memcpy(&f, &i, 4); return f;
}
__device__ __forceinline__ u16 f2us(float f){
  unsigned int i; __builtin_memcpy(&i, &f, 4);
  unsigned int r = i + 0x7fffu + ((i >> 16) & 1u);
  return (u16)(r >> 16);
}
__device__ __forceinline__ f4v MFMA_B16(s8v a, s8v b, f4v c){
  return __builtin_amdgcn_mfma_f32_16x16x32_bf16(a, b, c, 0, 0, 0);
}

typedef const __attribute__((address_space(1))) void* gas_ptr;
typedef __attribute__((address_space(3))) void* las_ptr;
__device__ __forceinline__ void gload16(const void* g, void* l){
  __builtin_amdgcn_global_load_lds((gas_ptr)g, (las_ptr)l, 16, 0, 0);
}

// ---------------- rope table ----------------
__global__ void rope_table_kernel(float* __restrict__ cosT, float* __restrict__ sinT){
  int i = blockIdx.x * 256 + threadIdx.x;
  if (i >= S_ * 32) return;
  int s = i >> 5, f = i & 31;
  double inv = exp(-(double)f / 32.0 * log(10000.0));
  double t = (double)s * inv;
  cosT[i] = (float)cos(t);
  sinT[i] = (float)sin(t);
}

// ---------------- transpose + fp32->bf16 convert ----------------
__global__ __launch_bounds__(256) void ttc_kernel(const float* __restrict__ in, u16* __restrict__ outp,
                                                  int Kd, int Nd, size_t zs, int rowoff, int rowmul){
  __shared__ float tile[64][65];
  size_t ibase = (size_t)blockIdx.z * Kd * Nd;
  size_t obase = (size_t)blockIdx.z * zs;
  int k0 = blockIdx.y * 64, n0 = blockIdx.x * 64;
  int tid = threadIdx.x;
  int tx = tid & 15, ty = tid >> 4;
  #pragma unroll
  for (int pp = 0; pp < 4; pp++){
    int kk = pp * 16 + ty;
    f4v v = *(const f4v*)(in + ibase + (size_t)(k0 + kk) * Nd + n0 + tx * 4);
    tile[kk][tx * 4 + 0] = v[0];
    tile[kk][tx * 4 + 1] = v[1];
    tile[kk][tx * 4 + 2] = v[2];
    tile[kk][tx * 4 + 3] = v[3];
  }
  __syncthreads();
  #pragma unroll
  for (int pp = 0; pp < 4; pp++){
    int nn = pp * 16 + ty;
    s4v o;
    #pragma unroll
    for (int j = 0; j < 4; j++) o[j] = (short)f2us(tile[tx * 4 + j][nn]);
    *(s4v*)(outp + obase + (size_t)(rowoff + (n0 + nn) * rowmul) * Kd + k0 + tx * 4) = o;
  }
}

// ---------------- rmsnorm (bf16 out + optional f32 out) ----------------
__global__ __launch_bounds__(256) void rmsnorm_kernel(const float* __restrict__ in, const float* __restrict__ w,
                                                      u16* __restrict__ outb, float* __restrict__ outf, int D){
  int t = blockIdx.x;
  const float* row = in + (size_t)t * D;
  float ss = 0.f;
  for (int i = threadIdx.x * 4; i < D; i += 1024){
    f4v v = *(const f4v*)(row + i);
    ss += v[0]*v[0] + v[1]*v[1] + v[2]*v[2] + v[3]*v[3];
  }
  #pragma unroll
  for (int m = 1; m < 64; m <<= 1) ss += __shfl_xor(ss, m);
  __shared__ float red[4];
  if ((threadIdx.x & 63) == 0) red[threadIdx.x >> 6] = ss;
  __syncthreads();
  float tot = red[0] + red[1] + red[2] + red[3];
  float r = 1.0f / sqrtf(tot / (float)D + 1e-5f);
  for (int i = threadIdx.x * 4; i < D; i += 1024){
    f4v v = *(const f4v*)(row + i);
    f4v wv = *(const f4v*)(w + i);
    s4v ob;
    f4v of;
    #pragma unroll
    for (int j = 0; j < 4; j++){ of[j] = v[j] * r * wv[j]; ob[j] = (short)f2us(of[j]); }
    *(s4v*)(outb + (size_t)t * D + i) = ob;
    if (outf) *(f4v*)(outf + (size_t)t * D + i) = of;
  }
}

// ---------------- fused ffn rmsnorm + MoE routing (D = H_ = 2048, 8 elems/thread) ----------------
__global__ __launch_bounds__(256) void rmsnorm_route_kernel(const float* __restrict__ in, const float* __restrict__ w,
                                                            const float* __restrict__ cent, const float* __restrict__ bias,
                                                            u16* __restrict__ outb,
                                                            int* __restrict__ eidx, float* __restrict__ ew,
                                                            int* __restrict__ counts){
  int t = blockIdx.x;
  int tid = threadIdx.x;
  const float* row = in + (size_t)t * H_;
  int i0 = tid * 8;
  f4v v0 = *(const f4v*)(row + i0);
  f4v v1 = *(const f4v*)(row + i0 + 4);
  float ss = v0[0]*v0[0]+v0[1]*v0[1]+v0[2]*v0[2]+v0[3]*v0[3]
           + v1[0]*v1[0]+v1[1]*v1[1]+v1[2]*v1[2]+v1[3]*v1[3];
  #pragma unroll
  for (int m = 1; m < 64; m <<= 1) ss += __shfl_xor(ss, m);
  __shared__ float red[4];
  __shared__ float ered[4][E_];
  if ((tid & 63) == 0) red[tid >> 6] = ss;
  __syncthreads();
  float tot = red[0] + red[1] + red[2] + red[3];
  float r = 1.0f / sqrtf(tot / (float)H_ + 1e-5f);

  f4v w0 = *(const f4v*)(w + i0);
  f4v w1 = *(const f4v*)(w + i0 + 4);
  f4v of0, of1;
  s8v ob;
  #pragma unroll
  for (int j = 0; j < 4; j++){ of0[j] = v0[j] * r * w0[j]; ob[j] = (short)f2us(of0[j]); }
  #pragma unroll
  for (int j = 0; j < 4; j++){ of1[j] = v1[j] * r * w1[j]; ob[4 + j] = (short)f2us(of1[j]); }
  *(s8v*)(outb + (size_t)t * H_ + i0) = ob;

  float acc[E_];
  #pragma unroll
  for (int e = 0; e < E_; e++){
    f4v c0 = *(const f4v*)(cent + (size_t)e * H_ + i0);
    f4v c1 = *(const f4v*)(cent + (size_t)e * H_ + i0 + 4);
    acc[e] = of0[0]*c0[0]+of0[1]*c0[1]+of0[2]*c0[2]+of0[3]*c0[3]
           + of1[0]*c1[0]+of1[1]*c1[1]+of1[2]*c1[2]+of1[3]*c1[3];
  }
  #pragma unroll
  for (int m = 1; m < 64; m <<= 1)
    #pragma unroll
    for (int e = 0; e < E_; e++) acc[e] += __shfl_xor(acc[e], m);
  if ((tid & 63) == 0){
    #pragma unroll
    for (int e = 0; e < E_; e++) ered[tid >> 6][e] = acc[e];
  }
  __syncthreads();
  if (tid == 0){
    float s[E_], sb[E_];
    #pragma unroll
    for (int e = 0; e < E_; e++){
      float d = ered[0][e] + ered[1][e] + ered[2][e] + ered[3][e];
      s[e] = 1.f / (1.f + expf(-d));
      sb[e] = s[e] + bias[e];
    }
    int i0e = 0;
    #pragma unroll
    for (int e = 1; e < E_; e++) if (sb[e] > sb[i0e]) i0e = e;
    int i1e = -1;
    #pragma unroll
    for (int e = 0; e < E_; e++) if (e != i0e && (i1e < 0 || sb[e] > sb[i1e])) i1e = e;
    float w0e = s[i0e], w1e = s[i1e], nrm = w0e + w1e;
    eidx[t * 2] = i0e; eidx[t * 2 + 1] = i1e;
    ew[t * 2] = w0e / nrm; ew[t * 2 + 1] = w1e / nrm;
    atomicAdd(&counts[i0e], 1); atomicAdd(&counts[i1e], 1);
  }
}

// ---------------- bf16 MFMA GEMM core: 128x128, BK=32, 8 waves (2x4), 2-buffer counted-vmcnt (r12 config) ----------------
// OUTMODE: 0 f32, 1 bf16, 2 f32+resid, 4 split bf16/bf16, 5 split3 f32, 6 silu-pair bf16 (resid=roww)
template<int OUTMODE, bool AGATHER>
__device__ __forceinline__ void gemm_core(const u16* __restrict__ A, int lda,
                                          const u16* __restrict__ Bt, int K, int M,
                                          const int* __restrict__ arows,
                                          float* __restrict__ outf0, float* __restrict__ outf1,
                                          float* __restrict__ outf2,
                                          u16* __restrict__ outb0, u16* __restrict__ outb1,
                                          int ldc0, int ldc1, int split, int split2,
                                          const float* __restrict__ resid,
                                          int bm0, int bn0){
  __shared__ u16 As[2][128 * 32];
  __shared__ u16 Bs[2][128 * 32];
  int tid = threadIdx.x;
  int w = tid >> 6, lane = tid & 63;
  int wr = w >> 2, wc = w & 3;
  int g = lane >> 4, l16 = lane & 15;

  f4v acc[4][2];
  #pragma unroll
  for (int m = 0; m < 4; m++)
    #pragma unroll
    for (int n = 0; n < 2; n++) acc[m][n] = (f4v)0.0f;

  int c = tid;
  int row = c >> 2;
  int sc = (c & 3) ^ ((c >> 3) & 3);
  int grow = bm0 + row;
  int ar;
  if (AGATHER) ar = arows[(grow < M) ? grow : 0];
  else         ar = (grow < M) ? grow : 0;
  const u16* asrc = A + (size_t)ar * lda + sc * 8;
  const u16* bsrc = Bt + (size_t)(bn0 + row) * K + sc * 8;
  int dst = (w * 64) * 8;
  int apos = (g ^ ((l16 >> 1) & 3)) * 8;

  int nt = K >> 5;
  gload16(asrc, &As[0][dst]);
  gload16(bsrc, &Bs[0][dst]);

  int cur = 0;
  for (int t = 0; t < nt; ++t){
    if (t + 1 < nt){
      int kn = (t + 1) * 32;
      gload16(asrc + kn, &As[cur ^ 1][dst]);
      gload16(bsrc + kn, &Bs[cur ^ 1][dst]);
      asm volatile("s_waitcnt vmcnt(2)" ::: "memory");
    } else {
      asm volatile("s_waitcnt vmcnt(0)" ::: "memory");
    }
    __builtin_amdgcn_s_barrier();
    asm volatile("" ::: "memory");
    s8v af[4], bf[2];
    #pragma unroll
    for (int m = 0; m < 4; m++) af[m] = *(const s8v*)(&As[cur][(wr * 64 + m * 16 + l16) * 32 + apos]);
    #pragma unroll
    for (int n = 0; n < 2; n++) bf[n] = *(const s8v*)(&Bs[cur][(wc * 32 + n * 16 + l16) * 32 + apos]);
    __builtin_amdgcn_s_setprio(1);
    #pragma unroll
    for (int m = 0; m < 4; m++)
      #pragma unroll
      for (int n = 0; n < 2; n++)
        acc[m][n] = MFMA_B16(af[m], bf[n], acc[m][n]);
    __builtin_amdgcn_s_setprio(0);
    asm volatile("" ::: "memory");
    __builtin_amdgcn_s_barrier();
    cur ^= 1;
  }

  #pragma unroll
  for (int m = 0; m < 4; m++)
    #pragma unroll
    for (int n = 0; n < 2; n++){
      int ccol = bn0 + wc * 32 + n * 16 + l16;
      #pragma unroll
      for (int j = 0; j < 4; j++){
        int r = wr * 64 + m * 16 + g * 4 + j;
        int gr = bm0 + r;
        float v = acc[m][n][j];
        if (OUTMODE == 6){
          float other = __shfl_xor(v, 1);
          if (gr < M && (lane & 1) == 0){
            float wgt = resid[gr];
            float gm = v / (1.f + __expf(-v));
            outb0[(size_t)gr * ldc0 + (ccol >> 1)] = f2us(gm * other * wgt);
          }
          continue;
        }
        if (gr >= M) continue;
        if (OUTMODE == 0){
          outf0[(size_t)gr * ldc0 + ccol] = v;
        } else if (OUTMODE == 1){
          outb0[(size_t)gr * ldc0 + ccol] = f2us(v);
        } else if (OUTMODE == 2){
          outf0[(size_t)gr * ldc0 + ccol] = v + resid[(size_t)gr * ldc0 + ccol];
        } else if (OUTMODE == 4){
          if (ccol < split) outb0[(size_t)gr * ldc0 + ccol] = f2us(v);
          else              outb1[(size_t)gr * ldc1 + (ccol - split)] = f2us(v);
        } else { // 5
          if (ccol < split)       outf0[(size_t)gr * ldc0 + ccol] = v;
          else if (ccol < split2) outf1[(size_t)gr * ldc1 + (ccol - split)] = v;
          else if (ccol < split2 + 64) outf2[(size_t)gr * 64 + (ccol - split2)] = v;
        }
      }
    }
}

// ---------------- dense core: 64x128 tile, BK=32, 4 waves (2x2), 24KB LDS, counted-vmcnt ----------------
template<int OUTMODE>
__device__ __forceinline__ void gemm_core64(const u16* __restrict__ A, int lda,
                                            const u16* __restrict__ Bt, int K, int M,
                                            float* __restrict__ outf0, float* __restrict__ outf1,
                                            float* __restrict__ outf2,
                                            u16* __restrict__ outb0, u16* __restrict__ outb1,
                                            int ldc0, int ldc1, int split, int split2,
                                            const float* __restrict__ resid,
                                            int bm0, int bn0){
  __shared__ u16 As[2][64 * 32];
  __shared__ u16 Bs[2][128 * 32];
  int tid = threadIdx.x;
  int w = tid >> 6, lane = tid & 63;
  int wr = w >> 1, wc = w & 1;
  int g = lane >> 4, l16 = lane & 15;

  f4v acc[2][4];
  #pragma unroll
  for (int m = 0; m < 2; m++)
    #pragma unroll
    for (int n = 0; n < 4; n++) acc[m][n] = (f4v)0.0f;

  int ca = tid;
  int rowa = ca >> 2;
  int sca = (ca & 3) ^ ((ca >> 3) & 3);
  const u16* asrc = A + (size_t)(bm0 + rowa) * lda + sca * 8;
  int dsta = (w * 64) * 8;
  const u16* bsrc[2];
  int dstb[2];
  #pragma unroll
  for (int p = 0; p < 2; p++){
    int c = tid + p * 256;
    int rowb = c >> 2;
    int scb = (c & 3) ^ ((c >> 3) & 3);
    bsrc[p] = Bt + (size_t)(bn0 + rowb) * K + scb * 8;
    dstb[p] = (p * 256 + w * 64) * 8;
  }
  int apos = (g ^ ((l16 >> 1) & 3)) * 8;

  int nt = K >> 5;
  gload16(asrc, &As[0][dsta]);
  #pragma unroll
  for (int p = 0; p < 2; p++) gload16(bsrc[p], &Bs[0][dstb[p]]);

  int cur = 0;
  for (int t = 0; t < nt; ++t){
    if (t + 1 < nt){
      int kn = (t + 1) * 32;
      gload16(asrc + kn, &As[cur ^ 1][dsta]);
      #pragma unroll
      for (int p = 0; p < 2; p++) gload16(bsrc[p] + kn, &Bs[cur ^ 1][dstb[p]]);
      asm volatile("s_waitcnt vmcnt(3)" ::: "memory");
    } else {
      asm volatile("s_waitcnt vmcnt(0)" ::: "memory");
    }
    __builtin_amdgcn_s_barrier();
    asm volatile("" ::: "memory");
    s8v af[2], bf[4];
    #pragma unroll
    for (int m = 0; m < 2; m++) af[m] = *(const s8v*)(&As[cur][(wr * 32 + m * 16 + l16) * 32 + apos]);
    #pragma unroll
    for (int n = 0; n < 4; n++) bf[n] = *(const s8v*)(&Bs[cur][(wc * 64 + n * 16 + l16) * 32 + apos]);
    __builtin_amdgcn_s_setprio(1);
    #pragma unroll
    for (int m = 0; m < 2; m++)
      #pragma unroll
      for (int n = 0; n < 4; n++)
        acc[m][n] = MFMA_B16(af[m], bf[n], acc[m][n]);
    __builtin_amdgcn_s_setprio(0);
    asm volatile("" ::: "memory");
    __builtin_amdgcn_s_barrier();
    cur ^= 1;
  }

  #pragma unroll
  for (int m = 0; m < 2; m++)
    #pragma unroll
    for (int n = 0; n < 4; n++){
      int ccol = bn0 + wc * 64 + n * 16 + l16;
      #pragma unroll
      for (int j = 0; j < 4; j++){
        int r = wr * 32 + m * 16 + g * 4 + j;
        int gr = bm0 + r;
        if (gr >= M) continue;
        float v = acc[m][n][j];
        if (OUTMODE == 0){
          outf0[(size_t)gr * ldc0 + ccol] = v;
        } else if (OUTMODE == 1){
          outb0[(size_t)gr * ldc0 + ccol] = f2us(v);
        } else if (OUTMODE == 2){
          outf0[(size_t)gr * ldc0 + ccol] = v + resid[(size_t)gr * ldc0 + ccol];
        } else if (OUTMODE == 4){
          if (ccol < split) outb0[(size_t)gr * ldc0 + ccol] = f2us(v);
          else              outb1[(size_t)gr * ldc1 + (ccol - split)] = f2us(v);
        } else { // 5
          if (ccol < split)       outf0[(size_t)gr * ldc0 + ccol] = v;
          else if (ccol < split2) outf1[(size_t)gr * ldc1 + (ccol - split)] = v;
          else if (ccol < split2 + 64) outf2[(size_t)gr * 64 + (ccol - split2)] = v;
        }
      }
    }
}

template<int OUTMODE>
__global__ __launch_bounds__(256) void gemm_kernel64(const u16* __restrict__ A, int lda,
                                                     const u16* __restrict__ Bt, int K, int M,
                                                     float* __restrict__ outf0, float* __restrict__ outf1,
                                                     float* __restrict__ outf2,
                                                     u16* __restrict__ outb0, u16* __restrict__ outb1,
                                                     int ldc0, int ldc1, int split, int split2,
                                                     const float* __restrict__ resid){
  int gx = gridDim.x;
  int nwg = gx * gridDim.y;
  int orig = blockIdx.y * gx + blockIdx.x;
  int wg = orig;
  if ((nwg & 7) == 0) wg = (orig & 7) * (nwg >> 3) + (orig >> 3);
  int bx = wg % gx, by = wg / gx;
  gemm_core64<OUTMODE>(A, lda, Bt, K, M,
                       outf0, outf1, outf2, outb0, outb1, ldc0, ldc1, split, split2, resid,
                       by * 64, bx * 128);
}

// ---------------- build qcat/kcat [B][NH][S][192], 8 elems/thread ----------------
__global__ __launch_bounds__(256) void build_qcat_kernel(const u16* __restrict__ qbuf, const u16* __restrict__ qrb,
                                                         const float* __restrict__ cosT, const float* __restrict__ sinT,
                                                         u16* __restrict__ qcat){
  size_t i8 = ((size_t)blockIdx.x * 256 + threadIdx.x) * 8;
  const size_t total = (size_t)B_ * NH_ * S_ * DQK_;
  if (i8 >= total) return;
  int d = (int)(i8 % DQK_); size_t rem = i8 / DQK_;
  int s = (int)(rem % S_); rem /= S_;
  int h = (int)(rem % NH_); int b = (int)(rem / NH_);
  int t = b * S_ + s;
  s8v o;
  if (d < DH_){
    o = *(const s8v*)(qbuf + (size_t)t * H_ + h * DH_ + d);
  } else {
    int r0 = d - DH_;
    int rr0 = r0 & 31;
    const u16* qp = qrb + (size_t)t * (NH_ * R_) + h * R_;
    #pragma unroll
    for (int j = 0; j < 8; j++){
      float c = cosT[s * 32 + rr0 + j], sn = sinT[s * 32 + rr0 + j];
      float lo = us2f(qp[rr0 + j]), hi = us2f(qp[rr0 + 32 + j]);
      float val = (r0 < 32) ? (lo * c - hi * sn) : (hi * c + lo * sn);
      o[j] = (short)f2us(val);
    }
  }
  *(s8v*)(qcat + i8) = o;
}

__global__ __launch_bounds__(256) void build_kcat_kernel(const u16* __restrict__ kbuf, const float* __restrict__ krb,
                                                         const float* __restrict__ cosT, const float* __restrict__ sinT,
                                                         u16* __restrict__ kcat){
  size_t i8 = ((size_t)blockIdx.x * 256 + threadIdx.x) * 8;
  const size_t total = (size_t)B_ * NH_ * S_ * DQK_;
  if (i8 >= total) return;
  int d = (int)(i8 % DQK_); size_t rem = i8 / DQK_;
  int s = (int)(rem % S_); rem /= S_;
  int h = (int)(rem % NH_); int b = (int)(rem / NH_);
  int t = b * S_ + s;
  s8v o;
  if (d < DH_){
    o = *(const s8v*)(kbuf + (size_t)t * H_ + h * DH_ + d);
  } else {
    int r0 = d - DH_;
    int rr0 = r0 & 31;
    const float* kp = krb + (size_t)t * R_;
    #pragma unroll
    for (int j = 0; j < 8; j++){
      float c = cosT[s * 32 + rr0 + j], sn = sinT[s * 32 + rr0 + j];
      float lo = kp[rr0 + j], hi = kp[rr0 + 32 + j];
      float val = (r0 < 32) ? (lo * c - hi * sn) : (hi * c + lo * sn);
      o[j] = (short)f2us(val);
    }
  }
  *(s8v*)(kcat + i8) = o;
}

// ---------------- vT[b][h][d][s] = v[b][s][h*128+d] ----------------
__global__ __launch_bounds__(256) void build_vT_kernel(const u16* __restrict__ vbuf, u16* __restrict__ vT){
  __shared__ u16 tile[32][33];
  int bh = blockIdx.z; int b = bh >> 4, h = bh & 15;
  int s0 = blockIdx.x * 32, d0 = blockIdx.y * 32;
  int tx = threadIdx.x & 31, ty = threadIdx.x >> 5;
  for (int i = ty; i < 32; i += 8)
    tile[i][tx] = vbuf[(size_t)(b * S_ + s0 + i) * H_ + h * DH_ + d0 + tx];
  __syncthreads();
  for (int i = ty; i < 32; i += 8)
    vT[((size_t)bh * DH_ + d0 + i) * S_ + s0 + tx] = tile[tx][i];
}

// ---------------- flash attention: 4 waves/block, QBLK=64, KVBLK=64 ----------------
__global__ __launch_bounds__(256) void attn_kernel(const u16* __restrict__ qcat, const u16* __restrict__ kcat,
                                                   const u16* __restrict__ vT, u16* __restrict__ aout){
  __shared__ u16 Ks[64 * 192];
  __shared__ u16 Vs[128 * 64];
  __shared__ u16 Ps[4][16][72];

  int qb = (int)(gridDim.x - 1) - (int)blockIdx.x;
  int h = blockIdx.y, b = blockIdx.z;
  int bh = b * NH_ + h;
  int tid = threadIdx.x;
  int w = tid >> 6, lane = tid & 63;
  int g = lane >> 4, l16 = lane & 15;
  int qrow0 = qb * 64 + w * 16;
  int qglob = qrow0 + l16;
  int qmax = qrow0 + 15;
  const float scale = 0.07216878364870323f;

  s8v qf[6];
  const u16* qrow = qcat + ((size_t)bh * S_ + qglob) * DQK_;
  #pragma unroll
  for (int c = 0; c < 6; c++) qf[c] = *(const s8v*)(qrow + c * 32 + g * 8);

  int koff[6];
  #pragma unroll
  for (int i = 0; i < 6; i++){
    int ci = tid + i * 256;
    int row = ci / 24, cp = ci - row * 24;
    koff[i] = row * 192 + ((cp ^ (row & 7)) * 8);
  }
  int voff[4];
  #pragma unroll
  for (int i = 0; i < 4; i++){
    int ci = tid + i * 256;
    int d = ci >> 3, cp = ci & 7;
    voff[i] = d * S_ + ((cp ^ (d & 7)) * 8);
  }

  const u16* kbase_g = kcat + (size_t)bh * S_ * DQK_;
  const u16* vbase_g = vT + (size_t)bh * DH_ * S_;

  f4v o[8];
  #pragma unroll
  for (int i = 0; i < 8; i++) o[i] = (f4v)0.0f;
  float mrow = -1e30f, lrow = 0.0f;

  int nkt = qb + 1;
  for (int it = 0; it < nkt; it++){
    int kv0 = it * 64;
    const u16* ksrc = kbase_g + (size_t)kv0 * DQK_;
    #pragma unroll
    for (int i = 0; i < 6; i++) gload16(ksrc + koff[i], &Ks[(i * 256 + w * 64) * 8]);
    #pragma unroll
    for (int i = 0; i < 4; i++) gload16(vbase_g + kv0 + voff[i], &Vs[(i * 256 + w * 64) * 8]);
    __syncthreads();

    f4v st[4];
    #pragma unroll
    for (int kf = 0; kf < 4; kf++){
      f4v a = (f4v)0.0f;
      if (kv0 + kf * 16 <= qmax){
        int row = kf * 16 + l16;
        int sw = (row & 7);
        #pragma unroll
        for (int c = 0; c < 6; c++){
          s8v kfr = *(const s8v*)(&Ks[row * 192 + (((c * 4 + g) ^ sw) * 8)]);
          a = MFMA_B16(kfr, qf[c], a);
        }
      }
      st[kf] = a;
    }

    float sv[16];
    #pragma unroll
    for (int kf = 0; kf < 4; kf++)
      #pragma unroll
      for (int j = 0; j < 4; j++){
        int kk = kv0 + kf * 16 + g * 4 + j;
        sv[kf * 4 + j] = (kk <= qglob) ? st[kf][j] * scale : -1e30f;
      }

    float mt = sv[0];
    #pragma unroll
    for (int i = 1; i < 16; i++) mt = fmaxf(mt, sv[i]);
    mt = fmaxf(mt, __shfl_xor(mt, 16));
    mt = fmaxf(mt, __shfl_xor(mt, 32));
    float mnew = fmaxf(mrow, mt);
    float corr = __expf(mrow - mnew);
    float ps = 0.f;
    u16 pb[16];
    #pragma unroll
    for (int i = 0; i < 16; i++){ float pv = __expf(sv[i] - mnew); ps += pv; pb[i] = f2us(pv); }
    ps += __shfl_xor(ps, 16); ps += __shfl_xor(ps, 32);
    lrow = lrow * corr + ps;
    mrow = mnew;
    #pragma unroll
    for (int i = 0; i < 8; i++) o[i] *= corr;

    #pragma unroll
    for (int kf = 0; kf < 4; kf++){
      s4v pw;
      #pragma unroll
      for (int j = 0; j < 4; j++) pw[j] = (short)pb[kf * 4 + j];
      *(s4v*)(&Ps[w][l16][kf * 16 + g * 4]) = pw;
    }

    #pragma unroll
    for (int ks = 0; ks < 2; ks++){
      if (kv0 + ks * 32 <= qmax){
        s4v plo = *(const s4v*)(&Ps[w][l16][ks * 32 + g * 8]);
        s4v phi = *(const s4v*)(&Ps[w][l16][ks * 32 + g * 8 + 4]);
        s8v pf;
        pf[0] = plo[0]; pf[1] = plo[1]; pf[2] = plo[2]; pf[3] = plo[3];
        pf[4] = phi[0]; pf[5] = phi[1]; pf[6] = phi[2]; pf[7] = phi[3];
        #pragma unroll
        for (int dt = 0; dt < 8; dt++){
          int d = dt * 16 + l16;
          s8v vf = *(const s8v*)(&Vs[d * 64 + ((((ks * 4 + g) ^ (d & 7))) * 8)]);
          o[dt] = MFMA_B16(vf, pf, o[dt]);
        }
      }
    }
    __syncthreads();
  }

  float inv = 1.0f / lrow;
  int trow = b * S_ + qglob;
  #pragma unroll
  for (int dt = 0; dt < 8; dt++){
    s4v wv;
    #pragma unroll
    for (int j = 0; j < 4; j++) wv[j] = (short)f2us(o[dt][j] * inv);
    *(s4v*)(aout + (size_t)trow * H_ + h * DH_ + dt * 16 + g * 4) = wv;
  }
}

__global__ void scan_kernel(int* __restrict__ meta){
  if (threadIdx.x == 0 && blockIdx.x == 0){
    int off = 0;
    for (int e = 0; e < E_; e++){ meta[16 + e] = off; meta[32 + e] = meta[e]; off += meta[e]; }
    meta[16 + 8] = 4096; meta[32 + 8] = T_;
    meta[16 + 9] = 4096 + T_; meta[32 + 9] = T_;
  }
}

__global__ void fill_kernel(const int* __restrict__ eidx, const float* __restrict__ ew,
                            int* __restrict__ meta, int* __restrict__ rowlist, float* __restrict__ roww,
                            int* __restrict__ slotidx){
  int t = blockIdx.x * 256 + threadIdx.x;
  if (t >= T_) return;
  for (int j = 0; j < 2; j++){
    int e = eidx[t * 2 + j];
    int p = atomicAdd(&meta[8 + e], 1);
    int slot = meta[16 + e] + p;
    rowlist[slot] = t; roww[slot] = ew[t * 2 + j];
    slotidx[t * 2 + j] = slot;
  }
}

__global__ void init_shared_kernel(int* __restrict__ rowlist, float* __restrict__ roww){
  int i = blockIdx.x * 256 + threadIdx.x;
  if (i >= 2 * T_) return;
  rowlist[4096 + i] = i & (T_ - 1);
  roww[4096 + i] = 0.1f;
}

// ---------------- MoE GEMM wrappers ----------------
// w13T: per expert [2048 rows][K=2048]; row 2j = w1 col j, row 2j+1 = w3 col j (interleaved)
__global__ __launch_bounds__(512) void moe_gemm13_kernel(const u16* __restrict__ h2b,
    const u16* __restrict__ w13T, const u16* __restrict__ w13sT,
    const int* __restrict__ rowlist, const int* __restrict__ listoff, const int* __restrict__ cnt2,
    const float* __restrict__ roww, u16* __restrict__ ub){
  int e = blockIdx.z;
  int cnt = cnt2[e];
  if ((int)(blockIdx.y * 128) >= cnt) return;
  const u16* Bt = (e < 8) ? w13T + (size_t)e * 2048 * H_ : w13sT + (size_t)(e - 8) * 2048 * H_;
  int loff = listoff[e];
  gemm_core<6, true>(h2b, H_, Bt, H_, cnt, rowlist + loff,
                     nullptr, nullptr, nullptr, ub + (size_t)loff * I_, nullptr,
                     I_, 0, 0, 0, roww + loff,
                     blockIdx.y * 128, blockIdx.x * 128);
}

__global__ __launch_bounds__(512) void moe_gemm2_kernel(const u16* __restrict__ ub,
    const u16* __restrict__ w2T, const u16* __restrict__ w2sT,
    const int* __restrict__ listoff, const int* __restrict__ cnt2,
    u16* __restrict__ o2){
  int e = blockIdx.z;
  int cnt = cnt2[e];
  if ((int)(blockIdx.y * 128) >= cnt) return;
  const u16* Bt = (e < 8) ? w2T + (size_t)e * H_ * I_ : w2sT + (size_t)(e - 8) * H_ * I_;
  int loff = listoff[e];
  gemm_core<1, false>(ub + (size_t)loff * I_, I_, Bt, I_, cnt, nullptr,
                      nullptr, nullptr, nullptr, o2 + (size_t)loff * H_, nullptr,
                      H_, 0, 0, 0, nullptr,
                      blockIdx.y * 128, blockIdx.x * 128);
}

__global__ __launch_bounds__(256) void combine_kernel(const float* __restrict__ x1, const u16* __restrict__ o2,
                                                      const int* __restrict__ slotidx, float* __restrict__ out){
  int t = blockIdx.x;
  int s0 = slotidx[2 * t], s1 = slotidx[2 * t + 1];
  const u16* r0 = o2 + (size_t)s0 * H_;
  const u16* r1 = o2 + (size_t)s1 * H_;
  const u16* r2 = o2 + (size_t)(4096 + t) * H_;
  const u16* r3 = o2 + (size_t)(4096 + T_ + t) * H_;
  const float* rx = x1 + (size_t)t * H_;
  float* ro = out + (size_t)t * H_;
  int c = threadIdx.x * 8;
  s8v v0 = *(const s8v*)(r0 + c);
  s8v v1 = *(const s8v*)(r1 + c);
  s8v v2 = *(const s8v*)(r2 + c);
  s8v v3 = *(const s8v*)(r3 + c);
  #pragma unroll
  for (int j = 0; j < 8; j++){
    ro[c + j] = rx[c + j] + us2f((u16)v0[j]) + us2f((u16)v1[j]) + us2f((u16)v2[j]) + us2f((u16)v3[j]);
  }
}

// ============================================================
extern "C" void kernel_launch(void* const* d_in, const int* in_sizes, int n_in,
                              void* d_out, int out_size, void* d_ws, size_t ws_size,
                              hipStream_t stream){
  const float* x    = (const float*)d_in[0];
  const float* anw  = (const float*)d_in[1];
  const float* fnw  = (const float*)d_in[2];
  const float* Wdq  = (const float*)d_in[3];
  const float* qnw  = (const float*)d_in[4];
  const float* Wuq  = (const float*)d_in[5];
  const float* Wqr  = (const float*)d_in[6];
  const float* Wdkv = (const float*)d_in[7];
  const float* kvnw = (const float*)d_in[8];
  const float* Wuk  = (const float*)d_in[9];
  const float* Wuv  = (const float*)d_in[10];
  const float* Wkr  = (const float*)d_in[11];
  const float* Wo   = (const float*)d_in[12];
  const float* cent = (const float*)d_in[13];
  const float* ebias= (const float*)d_in[14];
  const float* w1   = (const float*)d_in[15];
  const float* w3   = (const float*)d_in[16];
  const float* w2   = (const float*)d_in[17];
  const float* w1s  = (const float*)d_in[18];
  const float* w3s  = (const float*)d_in[19];
  const float* w2s  = (const float*)d_in[20];
  float* out = (float*)d_out;

  char* p = (char*)d_ws;
  auto alloc = [&](size_t bytes)->void*{
    void* r = (void*)p; p += (bytes + 255) & ~(size_t)255; return r;
  };

  // ---- persistent region ----
  float* cosT = (float*)alloc((size_t)S_ * 32 * 4);
  float* sinT = (float*)alloc((size_t)S_ * 32 * 4);
  u16* WdqkvT = (u16*)alloc((size_t)1664 * H_ * 2);   // rows: 0-1023 Wdq^T, 1024-1535 Wdkv^T, 1536-1599 Wkr^T, 1600-1663 zero
  u16* WuqrT  = (u16*)alloc((size_t)3072 * CQ_ * 2);
  u16* WukvT  = (u16*)alloc((size_t)4096 * CKV_ * 2);
  u16* WoT   = (u16*)alloc((size_t)H_ * H_ * 2);
  u16* w13T  = (u16*)alloc((size_t)E_ * 2048 * H_ * 2);
  u16* w2T   = (u16*)alloc((size_t)E_ * H_ * I_ * 2);
  u16* w13sT = (u16*)alloc((size_t)NS_ * 2048 * H_ * 2);
  u16* w2sT  = (u16*)alloc((size_t)NS_ * H_ * I_ * 2);
  float* x1  = (float*)alloc((size_t)T_ * H_ * 4);
  u16* h2b   = (u16*)alloc((size_t)T_ * H_ * 2);
  int* meta  = (int*)alloc(64 * 4);
  int* eidx  = (int*)alloc((size_t)T_ * 2 * 4);
  float* ew  = (float*)alloc((size_t)T_ * 2 * 4);
  int* rowlist = (int*)alloc(8192 * 4);
  float* roww  = (float*)alloc(8192 * 4);
  int* slotidx = (int*)alloc((size_t)T_ * 2 * 4);

  // ---- phase-overlapped region ----
  char* mark = p;
  u16* hn    = (u16*)alloc((size_t)T_ * H_ * 2);
  float* tq  = (float*)alloc((size_t)T_ * CQ_ * 4);
  u16* cq    = (u16*)alloc((size_t)T_ * CQ_ * 2);
  u16* qbuf  = (u16*)alloc((size_t)T_ * H_ * 2);
  u16* qrb   = (u16*)alloc((size_t)T_ * NH_ * R_ * 2);
  float* tkv = (float*)alloc((size_t)T_ * CKV_ * 4);
  u16* ckv   = (u16*)alloc((size_t)T_ * CKV_ * 2);
  u16* kbuf  = (u16*)alloc((size_t)T_ * H_ * 2);
  u16* vbuf  = (u16*)alloc((size_t)T_ * H_ * 2);
  float* krb = (float*)alloc((size_t)T_ * R_ * 4);
  u16* qcat  = (u16*)alloc((size_t)B_ * NH_ * S_ * DQK_ * 2);
  u16* kcat  = (u16*)alloc((size_t)B_ * NH_ * S_ * DQK_ * 2);
  u16* vT    = (u16*)alloc((size_t)B_ * NH_ * DH_ * S_ * 2);
  u16* aout  = (u16*)alloc((size_t)T_ * H_ * 2);

  p = mark;
  u16* ub  = (u16*)alloc((size_t)8192 * I_ * 2);
  u16* o2  = (u16*)alloc((size_t)8192 * H_ * 2);

  dim3 b256(256), b64(64), b512(512);

  hipMemsetAsync(meta, 0, 64 * 4, stream);
  hipMemsetAsync(WdqkvT + (size_t)1600 * H_, 0, (size_t)64 * H_ * 2, stream);

  rope_table_kernel<<<dim3((S_ * 32 + 255) / 256), b256, 0, stream>>>(cosT, sinT);

  ttc_kernel<<<dim3(CQ_ / 64, H_ / 64, 1),  b256, 0, stream>>>(Wdq,  WdqkvT, H_,  CQ_, 0, 0, 1);
  ttc_kernel<<<dim3(CKV_ / 64, H_ / 64, 1), b256, 0, stream>>>(Wdkv, WdqkvT, H_,  CKV_, 0, 1024, 1);
  ttc_kernel<<<dim3(1, H_ / 64, 1),         b256, 0, stream>>>(Wkr,  WdqkvT, H_,  R_, 0, 1536, 1);
  ttc_kernel<<<dim3(H_ / 64, CQ_ / 64, 1),  b256, 0, stream>>>(Wuq,  WuqrT,  CQ_, H_, 0, 0, 1);
  ttc_kernel<<<dim3(1024 / 64, CQ_ / 64, 1), b256, 0, stream>>>(Wqr, WuqrT,  CQ_, 1024, 0, 2048, 1);
  ttc_kernel<<<dim3(H_ / 64, CKV_ / 64, 1), b256, 0, stream>>>(Wuk,  WukvT,  CKV_, H_, 0, 0, 1);
  ttc_kernel<<<dim3(H_ / 64, CKV_ / 64, 1), b256, 0, stream>>>(Wuv,  WukvT,  CKV_, H_, 0, 2048, 1);
  ttc_kernel<<<dim3(H_ / 64, H_ / 64, 1),   b256, 0, stream>>>(Wo,   WoT,    H_,  H_, 0, 0, 1);
  ttc_kernel<<<dim3(I_ / 64, H_ / 64, E_),  b256, 0, stream>>>(w1,  w13T, H_, I_, (size_t)2048 * H_, 0, 2);
  ttc_kernel<<<dim3(I_ / 64, H_ / 64, E_),  b256, 0, stream>>>(w3,  w13T, H_, I_, (size_t)2048 * H_, 1, 2);
  ttc_kernel<<<dim3(H_ / 64, I_ / 64, E_),  b256, 0, stream>>>(w2,  w2T,  I_, H_, (size_t)H_ * I_, 0, 1);
  ttc_kernel<<<dim3(I_ / 64, H_ / 64, NS_), b256, 0, stream>>>(w1s, w13sT, H_, I_, (size_t)2048 * H_, 0, 2);
  ttc_kernel<<<dim3(I_ / 64, H_ / 64, NS_), b256, 0, stream>>>(w3s, w13sT, H_, I_, (size_t)2048 * H_, 1, 2);
  ttc_kernel<<<dim3(H_ / 64, I_ / 64, NS_), b256, 0, stream>>>(w2s, w2sT, I_, H_, (size_t)H_ * I_, 0, 1);

  rmsnorm_kernel<<<T_, b256, 0, stream>>>(x, anw, hn, nullptr, H_);

  // fused dq+dkv+kr: N=1664, splits 1024/1536 -> tq, tkv, krb(raw)
  gemm_kernel64<5><<<dim3(1664 / 128, T_ / 64), b256, 0, stream>>>(hn, H_, WdqkvT, H_, T_,
      tq, tkv, krb, nullptr, nullptr, CQ_, CKV_, 1024, 1536, nullptr);
  rmsnorm_kernel<<<T_, b256, 0, stream>>>(tq, qnw, cq, nullptr, CQ_);
  rmsnorm_kernel<<<T_, b256, 0, stream>>>(tkv, kvnw, ckv, nullptr, CKV_);
  gemm_kernel64<4><<<dim3(3072 / 128, T_ / 64), b256, 0, stream>>>(cq, CQ_, WuqrT, CQ_, T_,
      nullptr, nullptr, nullptr, qbuf, qrb, H_, NH_ * R_, 2048, 0, nullptr);
  gemm_kernel64<4><<<dim3(4096 / 128, T_ / 64), b256, 0, stream>>>(ckv, CKV_, WukvT, CKV_, T_,
      nullptr, nullptr, nullptr, kbuf, vbuf, H_, H_, 2048, 0, nullptr);

  size_t qct = (size_t)B_ * NH_ * S_ * DQK_;
  build_qcat_kernel<<<dim3((qct / 8 + 255) / 256), b256, 0, stream>>>(qbuf, qrb, cosT, sinT, qcat);
  build_kcat_kernel<<<dim3((qct / 8 + 255) / 256), b256, 0, stream>>>(kbuf, krb, cosT, sinT, kcat);
  build_vT_kernel<<<dim3(S_ / 32, DH_ / 32, B_ * NH_), b256, 0, stream>>>(vbuf, vT);

  attn_kernel<<<dim3(S_ / 64, NH_, B_), b256, 0, stream>>>(qcat, kcat, vT, aout);

  gemm_kernel64<2><<<dim3(H_ / 128, T_ / 64), b256, 0, stream>>>(aout, H_, WoT, H_, T_,
      x1, nullptr, nullptr, nullptr, nullptr, H_, 0, 0, 0, x);

  rmsnorm_route_kernel<<<T_, b256, 0, stream>>>(x1, fnw, cent, ebias, h2b, eidx, ew, meta);
  scan_kernel<<<dim3(1), b64, 0, stream>>>(meta);
  fill_kernel<<<dim3((T_ + 255) / 256), b256, 0, stream>>>(eidx, ew, meta, rowlist, roww, slotidx);
  init_shared_kernel<<<dim3((2 * T_ + 255) / 256), b256, 0, stream>>>(rowlist, roww);

  moe_gemm13_kernel<<<dim3(2048 / 128, 16, 10), b512, 0, stream>>>(h2b, w13T, w13sT,
      rowlist, meta + 16, meta + 32, roww, ub);
  moe_gemm2_kernel<<<dim3(H_ / 128, 16, 10), b512, 0, stream>>>(ub, w2T, w2sT,
      meta + 16, meta + 32, o2);

  combine_kernel<<<T_, b256, 0, stream>>>(x1, o2, slotidx, out);
}

// Round 15
// 596.911 us; speedup vs baseline: 1.0518x; 1.0096x over previous
//
#include <hip/hip_runtime.h>
#include <hip/hip_bf16.h>
#include <math.h>

typedef unsigned short u16;
typedef __attribute__((ext_vector_type(8))) short s8v;
typedef __attribute__((ext_vector_type(4))) short s4v;
typedef __attribute__((ext_vector_type(4))) float f4v;

#define B_   2
#define S_   1024
#define T_   2048
#define H_   2048
#define NH_  16
#define DH_  128
#define R_   64
#define CQ_  1024
#define CKV_ 512
#define DQK_ 192
#define E_   8
#define I_   1024
#define NS_  2

__device__ __forceinline__ float us2f(u16 u){
  unsigned int i = ((unsigned int)u) << 16; float f; __builtin_memcpy(&f, &i, 4); return f;
}
__device__ __forceinline__ u16 f2us(float f){
  unsigned int i; __builtin_memcpy(&i, &f, 4);
  unsigned int r = i + 0x7fffu + ((i >> 16) & 1u);
  return (u16)(r >> 16);
}
__device__ __forceinline__ f4v MFMA_B16(s8v a, s8v b, f4v c){
  return __builtin_amdgcn_mfma_f32_16x16x32_bf16(a, b, c, 0, 0, 0);
}

typedef const __attribute__((address_space(1))) void* gas_ptr;
typedef __attribute__((address_space(3))) void* las_ptr;
__device__ __forceinline__ void gload16(const void* g, void* l){
  __builtin_amdgcn_global_load_lds((gas_ptr)g, (las_ptr)l, 16, 0, 0);
}

// ---------------- rope table (fp32) ----------------
__global__ void rope_table_kernel(float* __restrict__ cosT, float* __restrict__ sinT){
  int i = blockIdx.x * 256 + threadIdx.x;
  if (i >= S_ * 32) return;
  int s = i >> 5, f = i & 31;
  float inv = __expf(-(float)f * (9.210340371976184f / 32.0f));  // 10000^(-f/32)
  float t = (float)s * inv;
  cosT[i] = cosf(t);
  sinT[i] = sinf(t);
}

// ---------------- transpose + fp32->bf16 convert ----------------
__global__ __launch_bounds__(256) void ttc_kernel(const float* __restrict__ in, u16* __restrict__ outp,
                                                  int Kd, int Nd, size_t zs, int rowoff, int rowmul){
  __shared__ float tile[64][65];
  size_t ibase = (size_t)blockIdx.z * Kd * Nd;
  size_t obase = (size_t)blockIdx.z * zs;
  int k0 = blockIdx.y * 64, n0 = blockIdx.x * 64;
  int tid = threadIdx.x;
  int tx = tid & 15, ty = tid >> 4;
  #pragma unroll
  for (int pp = 0; pp < 4; pp++){
    int kk = pp * 16 + ty;
    f4v v = *(const f4v*)(in + ibase + (size_t)(k0 + kk) * Nd + n0 + tx * 4);
    tile[kk][tx * 4 + 0] = v[0];
    tile[kk][tx * 4 + 1] = v[1];
    tile[kk][tx * 4 + 2] = v[2];
    tile[kk][tx * 4 + 3] = v[3];
  }
  __syncthreads();
  #pragma unroll
  for (int pp = 0; pp < 4; pp++){
    int nn = pp * 16 + ty;
    s4v o;
    #pragma unroll
    for (int j = 0; j < 4; j++) o[j] = (short)f2us(tile[tx * 4 + j][nn]);
    *(s4v*)(outp + obase + (size_t)(rowoff + (n0 + nn) * rowmul) * Kd + k0 + tx * 4) = o;
  }
}

// ---------------- rmsnorm (bf16 out + optional f32 out) ----------------
__global__ __launch_bounds__(256) void rmsnorm_kernel(const float* __restrict__ in, const float* __restrict__ w,
                                                      u16* __restrict__ outb, float* __restrict__ outf, int D){
  int t = blockIdx.x;
  const float* row = in + (size_t)t * D;
  float ss = 0.f;
  for (int i = threadIdx.x * 4; i < D; i += 1024){
    f4v v = *(const f4v*)(row + i);
    ss += v[0]*v[0] + v[1]*v[1] + v[2]*v[2] + v[3]*v[3];
  }
  #pragma unroll
  for (int m = 1; m < 64; m <<= 1) ss += __shfl_xor(ss, m);
  __shared__ float red[4];
  if ((threadIdx.x & 63) == 0) red[threadIdx.x >> 6] = ss;
  __syncthreads();
  float tot = red[0] + red[1] + red[2] + red[3];
  float r = 1.0f / sqrtf(tot / (float)D + 1e-5f);
  for (int i = threadIdx.x * 4; i < D; i += 1024){
    f4v v = *(const f4v*)(row + i);
    f4v wv = *(const f4v*)(w + i);
    s4v ob;
    f4v of;
    #pragma unroll
    for (int j = 0; j < 4; j++){ of[j] = v[j] * r * wv[j]; ob[j] = (short)f2us(of[j]); }
    *(s4v*)(outb + (size_t)t * D + i) = ob;
    if (outf) *(f4v*)(outf + (size_t)t * D + i) = of;
  }
}

// ---------------- fused ffn rmsnorm + MoE routing ----------------
__global__ __launch_bounds__(256) void rmsnorm_route_kernel(const float* __restrict__ in, const float* __restrict__ w,
                                                            const float* __restrict__ cent, const float* __restrict__ bias,
                                                            u16* __restrict__ outb,
                                                            int* __restrict__ eidx, float* __restrict__ ew,
                                                            int* __restrict__ counts){
  int t = blockIdx.x;
  int tid = threadIdx.x;
  const float* row = in + (size_t)t * H_;
  int i0 = tid * 8;
  f4v v0 = *(const f4v*)(row + i0);
  f4v v1 = *(const f4v*)(row + i0 + 4);
  float ss = v0[0]*v0[0]+v0[1]*v0[1]+v0[2]*v0[2]+v0[3]*v0[3]
           + v1[0]*v1[0]+v1[1]*v1[1]+v1[2]*v1[2]+v1[3]*v1[3];
  #pragma unroll
  for (int m = 1; m < 64; m <<= 1) ss += __shfl_xor(ss, m);
  __shared__ float red[4];
  __shared__ float ered[4][E_];
  if ((tid & 63) == 0) red[tid >> 6] = ss;
  __syncthreads();
  float tot = red[0] + red[1] + red[2] + red[3];
  float r = 1.0f / sqrtf(tot / (float)H_ + 1e-5f);

  f4v w0 = *(const f4v*)(w + i0);
  f4v w1 = *(const f4v*)(w + i0 + 4);
  f4v of0, of1;
  s8v ob;
  #pragma unroll
  for (int j = 0; j < 4; j++){ of0[j] = v0[j] * r * w0[j]; ob[j] = (short)f2us(of0[j]); }
  #pragma unroll
  for (int j = 0; j < 4; j++){ of1[j] = v1[j] * r * w1[j]; ob[4 + j] = (short)f2us(of1[j]); }
  *(s8v*)(outb + (size_t)t * H_ + i0) = ob;

  float acc[E_];
  #pragma unroll
  for (int e = 0; e < E_; e++){
    f4v c0 = *(const f4v*)(cent + (size_t)e * H_ + i0);
    f4v c1 = *(const f4v*)(cent + (size_t)e * H_ + i0 + 4);
    acc[e] = of0[0]*c0[0]+of0[1]*c0[1]+of0[2]*c0[2]+of0[3]*c0[3]
           + of1[0]*c1[0]+of1[1]*c1[1]+of1[2]*c1[2]+of1[3]*c1[3];
  }
  #pragma unroll
  for (int m = 1; m < 64; m <<= 1)
    #pragma unroll
    for (int e = 0; e < E_; e++) acc[e] += __shfl_xor(acc[e], m);
  if ((tid & 63) == 0){
    #pragma unroll
    for (int e = 0; e < E_; e++) ered[tid >> 6][e] = acc[e];
  }
  __syncthreads();
  if (tid == 0){
    float s[E_], sb[E_];
    #pragma unroll
    for (int e = 0; e < E_; e++){
      float d = ered[0][e] + ered[1][e] + ered[2][e] + ered[3][e];
      s[e] = 1.f / (1.f + expf(-d));
      sb[e] = s[e] + bias[e];
    }
    int i0e = 0;
    #pragma unroll
    for (int e = 1; e < E_; e++) if (sb[e] > sb[i0e]) i0e = e;
    int i1e = -1;
    #pragma unroll
    for (int e = 0; e < E_; e++) if (e != i0e && (i1e < 0 || sb[e] > sb[i1e])) i1e = e;
    float w0e = s[i0e], w1e = s[i1e], nrm = w0e + w1e;
    eidx[t * 2] = i0e; eidx[t * 2 + 1] = i1e;
    ew[t * 2] = w0e / nrm; ew[t * 2 + 1] = w1e / nrm;
    atomicAdd(&counts[i0e], 1); atomicAdd(&counts[i1e], 1);
  }
}

// ---------------- bf16 MFMA GEMM core: 128x128, BK=32, 8 waves (2x4), 2-buffer counted-vmcnt ----------------
// OUTMODE: 0 f32, 1 bf16, 2 f32+resid, 4 split bf16/bf16, 5 split3 f32, 6 silu-pair bf16 (resid=roww)
template<int OUTMODE, bool AGATHER>
__device__ __forceinline__ void gemm_core(const u16* __restrict__ A, int lda,
                                          const u16* __restrict__ Bt, int K, int M,
                                          const int* __restrict__ arows,
                                          float* __restrict__ outf0, float* __restrict__ outf1,
                                          float* __restrict__ outf2,
                                          u16* __restrict__ outb0, u16* __restrict__ outb1,
                                          int ldc0, int ldc1, int split, int split2,
                                          const float* __restrict__ resid,
                                          int bm0, int bn0){
  __shared__ u16 As[2][128 * 32];
  __shared__ u16 Bs[2][128 * 32];
  int tid = threadIdx.x;
  int w = tid >> 6, lane = tid & 63;
  int wr = w >> 2, wc = w & 3;
  int g = lane >> 4, l16 = lane & 15;

  f4v acc[4][2];
  #pragma unroll
  for (int m = 0; m < 4; m++)
    #pragma unroll
    for (int n = 0; n < 2; n++) acc[m][n] = (f4v)0.0f;

  int c = tid;
  int row = c >> 2;
  int sc = (c & 3) ^ ((c >> 3) & 3);
  int grow = bm0 + row;
  int ar;
  if (AGATHER) ar = arows[(grow < M) ? grow : 0];
  else         ar = (grow < M) ? grow : 0;
  const u16* asrc = A + (size_t)ar * lda + sc * 8;
  const u16* bsrc = Bt + (size_t)(bn0 + row) * K + sc * 8;
  int dst = (w * 64) * 8;
  int apos = (g ^ ((l16 >> 1) & 3)) * 8;

  int nt = K >> 5;
  gload16(asrc, &As[0][dst]);
  gload16(bsrc, &Bs[0][dst]);

  int cur = 0;
  for (int t = 0; t < nt; ++t){
    if (t + 1 < nt){
      int kn = (t + 1) * 32;
      gload16(asrc + kn, &As[cur ^ 1][dst]);
      gload16(bsrc + kn, &Bs[cur ^ 1][dst]);
      asm volatile("s_waitcnt vmcnt(2)" ::: "memory");
    } else {
      asm volatile("s_waitcnt vmcnt(0)" ::: "memory");
    }
    __builtin_amdgcn_s_barrier();
    asm volatile("" ::: "memory");
    s8v af[4], bf[2];
    #pragma unroll
    for (int m = 0; m < 4; m++) af[m] = *(const s8v*)(&As[cur][(wr * 64 + m * 16 + l16) * 32 + apos]);
    #pragma unroll
    for (int n = 0; n < 2; n++) bf[n] = *(const s8v*)(&Bs[cur][(wc * 32 + n * 16 + l16) * 32 + apos]);
    __builtin_amdgcn_s_setprio(1);
    #pragma unroll
    for (int m = 0; m < 4; m++)
      #pragma unroll
      for (int n = 0; n < 2; n++)
        acc[m][n] = MFMA_B16(af[m], bf[n], acc[m][n]);
    __builtin_amdgcn_s_setprio(0);
    asm volatile("" ::: "memory");
    __builtin_amdgcn_s_barrier();
    cur ^= 1;
  }

  #pragma unroll
  for (int m = 0; m < 4; m++)
    #pragma unroll
    for (int n = 0; n < 2; n++){
      int ccol = bn0 + wc * 32 + n * 16 + l16;
      #pragma unroll
      for (int j = 0; j < 4; j++){
        int r = wr * 64 + m * 16 + g * 4 + j;
        int gr = bm0 + r;
        float v = acc[m][n][j];
        if (OUTMODE == 6){
          float other = __shfl_xor(v, 1);
          if (gr < M && (lane & 1) == 0){
            float wgt = resid[gr];
            float gm = v / (1.f + __expf(-v));
            outb0[(size_t)gr * ldc0 + (ccol >> 1)] = f2us(gm * other * wgt);
          }
          continue;
        }
        if (gr >= M) continue;
        if (OUTMODE == 0){
          outf0[(size_t)gr * ldc0 + ccol] = v;
        } else if (OUTMODE == 1){
          outb0[(size_t)gr * ldc0 + ccol] = f2us(v);
        } else if (OUTMODE == 2){
          outf0[(size_t)gr * ldc0 + ccol] = v + resid[(size_t)gr * ldc0 + ccol];
        } else if (OUTMODE == 4){
          if (ccol < split) outb0[(size_t)gr * ldc0 + ccol] = f2us(v);
          else              outb1[(size_t)gr * ldc1 + (ccol - split)] = f2us(v);
        } else { // 5
          if (ccol < split)       outf0[(size_t)gr * ldc0 + ccol] = v;
          else if (ccol < split2) outf1[(size_t)gr * ldc1 + (ccol - split)] = v;
          else if (ccol < split2 + 64) outf2[(size_t)gr * 64 + (ccol - split2)] = v;
        }
      }
    }
}

// ---------------- dense core: 64x128 tile, BK=32, 4 waves (2x2), 24KB LDS, counted-vmcnt ----------------
template<int OUTMODE>
__device__ __forceinline__ void gemm_core64(const u16* __restrict__ A, int lda,
                                            const u16* __restrict__ Bt, int K, int M,
                                            float* __restrict__ outf0, float* __restrict__ outf1,
                                            float* __restrict__ outf2,
                                            u16* __restrict__ outb0, u16* __restrict__ outb1,
                                            int ldc0, int ldc1, int split, int split2,
                                            const float* __restrict__ resid,
                                            int bm0, int bn0){
  __shared__ u16 As[2][64 * 32];
  __shared__ u16 Bs[2][128 * 32];
  int tid = threadIdx.x;
  int w = tid >> 6, lane = tid & 63;
  int wr = w >> 1, wc = w & 1;
  int g = lane >> 4, l16 = lane & 15;

  f4v acc[2][4];
  #pragma unroll
  for (int m = 0; m < 2; m++)
    #pragma unroll
    for (int n = 0; n < 4; n++) acc[m][n] = (f4v)0.0f;

  int ca = tid;
  int rowa = ca >> 2;
  int sca = (ca & 3) ^ ((ca >> 3) & 3);
  const u16* asrc = A + (size_t)(bm0 + rowa) * lda + sca * 8;
  int dsta = (w * 64) * 8;
  const u16* bsrc[2];
  int dstb[2];
  #pragma unroll
  for (int p = 0; p < 2; p++){
    int c = tid + p * 256;
    int rowb = c >> 2;
    int scb = (c & 3) ^ ((c >> 3) & 3);
    bsrc[p] = Bt + (size_t)(bn0 + rowb) * K + scb * 8;
    dstb[p] = (p * 256 + w * 64) * 8;
  }
  int apos = (g ^ ((l16 >> 1) & 3)) * 8;

  int nt = K >> 5;
  gload16(asrc, &As[0][dsta]);
  #pragma unroll
  for (int p = 0; p < 2; p++) gload16(bsrc[p], &Bs[0][dstb[p]]);

  int cur = 0;
  for (int t = 0; t < nt; ++t){
    if (t + 1 < nt){
      int kn = (t + 1) * 32;
      gload16(asrc + kn, &As[cur ^ 1][dsta]);
      #pragma unroll
      for (int p = 0; p < 2; p++) gload16(bsrc[p] + kn, &Bs[cur ^ 1][dstb[p]]);
      asm volatile("s_waitcnt vmcnt(3)" ::: "memory");
    } else {
      asm volatile("s_waitcnt vmcnt(0)" ::: "memory");
    }
    __builtin_amdgcn_s_barrier();
    asm volatile("" ::: "memory");
    s8v af[2], bf[4];
    #pragma unroll
    for (int m = 0; m < 2; m++) af[m] = *(const s8v*)(&As[cur][(wr * 32 + m * 16 + l16) * 32 + apos]);
    #pragma unroll
    for (int n = 0; n < 4; n++) bf[n] = *(const s8v*)(&Bs[cur][(wc * 64 + n * 16 + l16) * 32 + apos]);
    __builtin_amdgcn_s_setprio(1);
    #pragma unroll
    for (int m = 0; m < 2; m++)
      #pragma unroll
      for (int n = 0; n < 4; n++)
        acc[m][n] = MFMA_B16(af[m], bf[n], acc[m][n]);
    __builtin_amdgcn_s_setprio(0);
    asm volatile("" ::: "memory");
    __builtin_amdgcn_s_barrier();
    cur ^= 1;
  }

  #pragma unroll
  for (int m = 0; m < 2; m++)
    #pragma unroll
    for (int n = 0; n < 4; n++){
      int ccol = bn0 + wc * 64 + n * 16 + l16;
      #pragma unroll
      for (int j = 0; j < 4; j++){
        int r = wr * 32 + m * 16 + g * 4 + j;
        int gr = bm0 + r;
        if (gr >= M) continue;
        float v = acc[m][n][j];
        if (OUTMODE == 0){
          outf0[(size_t)gr * ldc0 + ccol] = v;
        } else if (OUTMODE == 1){
          outb0[(size_t)gr * ldc0 + ccol] = f2us(v);
        } else if (OUTMODE == 2){
          outf0[(size_t)gr * ldc0 + ccol] = v + resid[(size_t)gr * ldc0 + ccol];
        } else if (OUTMODE == 4){
          if (ccol < split) outb0[(size_t)gr * ldc0 + ccol] = f2us(v);
          else              outb1[(size_t)gr * ldc1 + (ccol - split)] = f2us(v);
        } else { // 5
          if (ccol < split)       outf0[(size_t)gr * ldc0 + ccol] = v;
          else if (ccol < split2) outf1[(size_t)gr * ldc1 + (ccol - split)] = v;
          else if (ccol < split2 + 64) outf2[(size_t)gr * 64 + (ccol - split2)] = v;
        }
      }
    }
}

template<int OUTMODE>
__global__ __launch_bounds__(256) void gemm_kernel64(const u16* __restrict__ A, int lda,
                                                     const u16* __restrict__ Bt, int K, int M,
                                                     float* __restrict__ outf0, float* __restrict__ outf1,
                                                     float* __restrict__ outf2,
                                                     u16* __restrict__ outb0, u16* __restrict__ outb1,
                                                     int ldc0, int ldc1, int split, int split2,
                                                     const float* __restrict__ resid){
  int gx = gridDim.x;
  int nwg = gx * gridDim.y;
  int orig = blockIdx.y * gx + blockIdx.x;
  int wg = orig;
  if ((nwg & 7) == 0) wg = (orig & 7) * (nwg >> 3) + (orig >> 3);
  int bx = wg % gx, by = wg / gx;
  gemm_core64<OUTMODE>(A, lda, Bt, K, M,
                       outf0, outf1, outf2, outb0, outb1, ldc0, ldc1, split, split2, resid,
                       by * 64, bx * 128);
}

// ---------------- merged build qcat+kcat: y=0 -> qcat, y=1 -> kcat ----------------
__global__ __launch_bounds__(256) void build_qkcat_kernel(const u16* __restrict__ qbuf, const u16* __restrict__ qrb,
                                                          const u16* __restrict__ kbuf, const float* __restrict__ krb,
                                                          const float* __restrict__ cosT, const float* __restrict__ sinT,
                                                          u16* __restrict__ qcat, u16* __restrict__ kcat){
  size_t i8 = ((size_t)blockIdx.x * 256 + threadIdx.x) * 8;
  const size_t total = (size_t)B_ * NH_ * S_ * DQK_;
  if (i8 >= total) return;
  int d = (int)(i8 % DQK_); size_t rem = i8 / DQK_;
  int s = (int)(rem % S_); rem /= S_;
  int h = (int)(rem % NH_); int b = (int)(rem / NH_);
  int t = b * S_ + s;
  s8v o;
  if (blockIdx.y == 0){
    if (d < DH_){
      o = *(const s8v*)(qbuf + (size_t)t * H_ + h * DH_ + d);
    } else {
      int r0 = d - DH_;
      int rr0 = r0 & 31;
      const u16* qp = qrb + (size_t)t * (NH_ * R_) + h * R_;
      #pragma unroll
      for (int j = 0; j < 8; j++){
        float c = cosT[s * 32 + rr0 + j], sn = sinT[s * 32 + rr0 + j];
        float lo = us2f(qp[rr0 + j]), hi = us2f(qp[rr0 + 32 + j]);
        float val = (r0 < 32) ? (lo * c - hi * sn) : (hi * c + lo * sn);
        o[j] = (short)f2us(val);
      }
    }
    *(s8v*)(qcat + i8) = o;
  } else {
    if (d < DH_){
      o = *(const s8v*)(kbuf + (size_t)t * H_ + h * DH_ + d);
    } else {
      int r0 = d - DH_;
      int rr0 = r0 & 31;
      const float* kp = krb + (size_t)t * R_;
      #pragma unroll
      for (int j = 0; j < 8; j++){
        float c = cosT[s * 32 + rr0 + j], sn = sinT[s * 32 + rr0 + j];
        float lo = kp[rr0 + j], hi = kp[rr0 + 32 + j];
        float val = (r0 < 32) ? (lo * c - hi * sn) : (hi * c + lo * sn);
        o[j] = (short)f2us(val);
      }
    }
    *(s8v*)(kcat + i8) = o;
  }
}

// ---------------- vT[b][h][d][s] = v[b][s][h*128+d] ----------------
__global__ __launch_bounds__(256) void build_vT_kernel(const u16* __restrict__ vbuf, u16* __restrict__ vT){
  __shared__ u16 tile[32][33];
  int bh = blockIdx.z; int b = bh >> 4, h = bh & 15;
  int s0 = blockIdx.x * 32, d0 = blockIdx.y * 32;
  int tx = threadIdx.x & 31, ty = threadIdx.x >> 5;
  for (int i = ty; i < 32; i += 8)
    tile[i][tx] = vbuf[(size_t)(b * S_ + s0 + i) * H_ + h * DH_ + d0 + tx];
  __syncthreads();
  for (int i = ty; i < 32; i += 8)
    vT[((size_t)bh * DH_ + d0 + i) * S_ + s0 + tx] = tile[tx][i];
}

// ---------------- flash attention: 4 waves/block, QBLK=64, KVBLK=64 ----------------
__global__ __launch_bounds__(256) void attn_kernel(const u16* __restrict__ qcat, const u16* __restrict__ kcat,
                                                   const u16* __restrict__ vT, u16* __restrict__ aout){
  __shared__ u16 Ks[64 * 192];
  __shared__ u16 Vs[128 * 64];
  __shared__ u16 Ps[4][16][72];

  int qb = (int)(gridDim.x - 1) - (int)blockIdx.x;
  int h = blockIdx.y, b = blockIdx.z;
  int bh = b * NH_ + h;
  int tid = threadIdx.x;
  int w = tid >> 6, lane = tid & 63;
  int g = lane >> 4, l16 = lane & 15;
  int qrow0 = qb * 64 + w * 16;
  int qglob = qrow0 + l16;
  int qmax = qrow0 + 15;
  const float scale = 0.07216878364870323f;

  s8v qf[6];
  const u16* qrow = qcat + ((size_t)bh * S_ + qglob) * DQK_;
  #pragma unroll
  for (int c = 0; c < 6; c++) qf[c] = *(const s8v*)(qrow + c * 32 + g * 8);

  int koff[6];
  #pragma unroll
  for (int i = 0; i < 6; i++){
    int ci = tid + i * 256;
    int row = ci / 24, cp = ci - row * 24;
    koff[i] = row * 192 + ((cp ^ (row & 7)) * 8);
  }
  int voff[4];
  #pragma unroll
  for (int i = 0; i < 4; i++){
    int ci = tid + i * 256;
    int d = ci >> 3, cp = ci & 7;
    voff[i] = d * S_ + ((cp ^ (d & 7)) * 8);
  }

  const u16* kbase_g = kcat + (size_t)bh * S_ * DQK_;
  const u16* vbase_g = vT + (size_t)bh * DH_ * S_;

  f4v o[8];
  #pragma unroll
  for (int i = 0; i < 8; i++) o[i] = (f4v)0.0f;
  float mrow = -1e30f, lrow = 0.0f;

  int nkt = qb + 1;
  for (int it = 0; it < nkt; it++){
    int kv0 = it * 64;
    const u16* ksrc = kbase_g + (size_t)kv0 * DQK_;
    #pragma unroll
    for (int i = 0; i < 6; i++) gload16(ksrc + koff[i], &Ks[(i * 256 + w * 64) * 8]);
    #pragma unroll
    for (int i = 0; i < 4; i++) gload16(vbase_g + kv0 + voff[i], &Vs[(i * 256 + w * 64) * 8]);
    __syncthreads();

    f4v st[4];
    #pragma unroll
    for (int kf = 0; kf < 4; kf++){
      f4v a = (f4v)0.0f;
      if (kv0 + kf * 16 <= qmax){
        int row = kf * 16 + l16;
        int sw = (row & 7);
        #pragma unroll
        for (int c = 0; c < 6; c++){
          s8v kfr = *(const s8v*)(&Ks[row * 192 + (((c * 4 + g) ^ sw) * 8)]);
          a = MFMA_B16(kfr, qf[c], a);
        }
      }
      st[kf] = a;
    }

    float sv[16];
    #pragma unroll
    for (int kf = 0; kf < 4; kf++)
      #pragma unroll
      for (int j = 0; j < 4; j++){
        int kk = kv0 + kf * 16 + g * 4 + j;
        sv[kf * 4 + j] = (kk <= qglob) ? st[kf][j] * scale : -1e30f;
      }

    float mt = sv[0];
    #pragma unroll
    for (int i = 1; i < 16; i++) mt = fmaxf(mt, sv[i]);
    mt = fmaxf(mt, __shfl_xor(mt, 16));
    mt = fmaxf(mt, __shfl_xor(mt, 32));
    float mnew = fmaxf(mrow, mt);
    float corr = __expf(mrow - mnew);
    float ps = 0.f;
    u16 pb[16];
    #pragma unroll
    for (int i = 0; i < 16; i++){ float pv = __expf(sv[i] - mnew); ps += pv; pb[i] = f2us(pv); }
    ps += __shfl_xor(ps, 16); ps += __shfl_xor(ps, 32);
    lrow = lrow * corr + ps;
    mrow = mnew;
    #pragma unroll
    for (int i = 0; i < 8; i++) o[i] *= corr;

    #pragma unroll
    for (int kf = 0; kf < 4; kf++){
      s4v pw;
      #pragma unroll
      for (int j = 0; j < 4; j++) pw[j] = (short)pb[kf * 4 + j];
      *(s4v*)(&Ps[w][l16][kf * 16 + g * 4]) = pw;
    }

    #pragma unroll
    for (int ks = 0; ks < 2; ks++){
      if (kv0 + ks * 32 <= qmax){
        s4v plo = *(const s4v*)(&Ps[w][l16][ks * 32 + g * 8]);
        s4v phi = *(const s4v*)(&Ps[w][l16][ks * 32 + g * 8 + 4]);
        s8v pf;
        pf[0] = plo[0]; pf[1] = plo[1]; pf[2] = plo[2]; pf[3] = plo[3];
        pf[4] = phi[0]; pf[5] = phi[1]; pf[6] = phi[2]; pf[7] = phi[3];
        #pragma unroll
        for (int dt = 0; dt < 8; dt++){
          int d = dt * 16 + l16;
          s8v vf = *(const s8v*)(&Vs[d * 64 + ((((ks * 4 + g) ^ (d & 7))) * 8)]);
          o[dt] = MFMA_B16(vf, pf, o[dt]);
        }
      }
    }
    __syncthreads();
  }

  float inv = 1.0f / lrow;
  int trow = b * S_ + qglob;
  #pragma unroll
  for (int dt = 0; dt < 8; dt++){
    s4v wv;
    #pragma unroll
    for (int j = 0; j < 4; j++) wv[j] = (short)f2us(o[dt][j] * inv);
    *(s4v*)(aout + (size_t)trow * H_ + h * DH_ + dt * 16 + g * 4) = wv;
  }
}

__global__ void scan_kernel(int* __restrict__ meta){
  if (threadIdx.x == 0 && blockIdx.x == 0){
    int off = 0;
    for (int e = 0; e < E_; e++){ meta[16 + e] = off; meta[32 + e] = meta[e]; off += meta[e]; }
    meta[16 + 8] = 4096; meta[32 + 8] = T_;
    meta[16 + 9] = 4096 + T_; meta[32 + 9] = T_;
  }
}

// fill + shared-expert list init merged
__global__ void fill_kernel(const int* __restrict__ eidx, const float* __restrict__ ew,
                            int* __restrict__ meta, int* __restrict__ rowlist, float* __restrict__ roww,
                            int* __restrict__ slotidx){
  int t = blockIdx.x * 256 + threadIdx.x;
  if (t >= T_) return;
  for (int j = 0; j < 2; j++){
    int e = eidx[t * 2 + j];
    int p = atomicAdd(&meta[8 + e], 1);
    int slot = meta[16 + e] + p;
    rowlist[slot] = t; roww[slot] = ew[t * 2 + j];
    slotidx[t * 2 + j] = slot;
  }
  rowlist[4096 + t] = t;       roww[4096 + t] = 0.1f;
  rowlist[4096 + T_ + t] = t;  roww[4096 + T_ + t] = 0.1f;
}

// ---------------- MoE GEMM wrappers ----------------
// w13T: per expert [2048 rows][K=2048]; row 2j = w1 col j, row 2j+1 = w3 col j (interleaved)
__global__ __launch_bounds__(512) void moe_gemm13_kernel(const u16* __restrict__ h2b,
    const u16* __restrict__ w13T, const u16* __restrict__ w13sT,
    const int* __restrict__ rowlist, const int* __restrict__ listoff, const int* __restrict__ cnt2,
    const float* __restrict__ roww, u16* __restrict__ ub){
  int e = blockIdx.z;
  int cnt = cnt2[e];
  if ((int)(blockIdx.y * 128) >= cnt) return;
  const u16* Bt = (e < 8) ? w13T + (size_t)e * 2048 * H_ : w13sT + (size_t)(e - 8) * 2048 * H_;
  int loff = listoff[e];
  gemm_core<6, true>(h2b, H_, Bt, H_, cnt, rowlist + loff,
                     nullptr, nullptr, nullptr, ub + (size_t)loff * I_, nullptr,
                     I_, 0, 0, 0, roww + loff,
                     blockIdx.y * 128, blockIdx.x * 128);
}

__global__ __launch_bounds__(512) void moe_gemm2_kernel(const u16* __restrict__ ub,
    const u16* __restrict__ w2T, const u16* __restrict__ w2sT,
    const int* __restrict__ listoff, const int* __restrict__ cnt2,
    u16* __restrict__ o2){
  int e = blockIdx.z;
  int cnt = cnt2[e];
  if ((int)(blockIdx.y * 128) >= cnt) return;
  const u16* Bt = (e < 8) ? w2T + (size_t)e * H_ * I_ : w2sT + (size_t)(e - 8) * H_ * I_;
  int loff = listoff[e];
  gemm_core<1, false>(ub + (size_t)loff * I_, I_, Bt, I_, cnt, nullptr,
                      nullptr, nullptr, nullptr, o2 + (size_t)loff * H_, nullptr,
                      H_, 0, 0, 0, nullptr,
                      blockIdx.y * 128, blockIdx.x * 128);
}

__global__ __launch_bounds__(256) void combine_kernel(const float* __restrict__ x1, const u16* __restrict__ o2,
                                                      const int* __restrict__ slotidx, float* __restrict__ out){
  int t = blockIdx.x;
  int s0 = slotidx[2 * t], s1 = slotidx[2 * t + 1];
  const u16* r0 = o2 + (size_t)s0 * H_;
  const u16* r1 = o2 + (size_t)s1 * H_;
  const u16* r2 = o2 + (size_t)(4096 + t) * H_;
  const u16* r3 = o2 + (size_t)(4096 + T_ + t) * H_;
  const float* rx = x1 + (size_t)t * H_;
  float* ro = out + (size_t)t * H_;
  int c = threadIdx.x * 8;
  s8v v0 = *(const s8v*)(r0 + c);
  s8v v1 = *(const s8v*)(r1 + c);
  s8v v2 = *(const s8v*)(r2 + c);
  s8v v3 = *(const s8v*)(r3 + c);
  #pragma unroll
  for (int j = 0; j < 8; j++){
    ro[c + j] = rx[c + j] + us2f((u16)v0[j]) + us2f((u16)v1[j]) + us2f((u16)v2[j]) + us2f((u16)v3[j]);
  }
}

// ============================================================
extern "C" void kernel_launch(void* const* d_in, const int* in_sizes, int n_in,
                              void* d_out, int out_size, void* d_ws, size_t ws_size,
                              hipStream_t stream){
  const float* x    = (const float*)d_in[0];
  const float* anw  = (const float*)d_in[1];
  const float* fnw  = (const float*)d_in[2];
  const float* Wdq  = (const float*)d_in[3];
  const float* qnw  = (const float*)d_in[4];
  const float* Wuq  = (const float*)d_in[5];
  const float* Wqr  = (const float*)d_in[6];
  const float* Wdkv = (const float*)d_in[7];
  const float* kvnw = (const float*)d_in[8];
  const float* Wuk  = (const float*)d_in[9];
  const float* Wuv  = (const float*)d_in[10];
  const float* Wkr  = (const float*)d_in[11];
  const float* Wo   = (const float*)d_in[12];
  const float* cent = (const float*)d_in[13];
  const float* ebias= (const float*)d_in[14];
  const float* w1   = (const float*)d_in[15];
  const float* w3   = (const float*)d_in[16];
  const float* w2   = (const float*)d_in[17];
  const float* w1s  = (const float*)d_in[18];
  const float* w3s  = (const float*)d_in[19];
  const float* w2s  = (const float*)d_in[20];
  float* out = (float*)d_out;

  char* p = (char*)d_ws;
  auto alloc = [&](size_t bytes)->void*{
    void* r = (void*)p; p += (bytes + 255) & ~(size_t)255; return r;
  };

  // ---- persistent region ----
  float* cosT = (float*)alloc((size_t)S_ * 32 * 4);
  float* sinT = (float*)alloc((size_t)S_ * 32 * 4);
  u16* WdqkvT = (u16*)alloc((size_t)1664 * H_ * 2);   // rows: 0-1023 Wdq^T, 1024-1535 Wdkv^T, 1536-1599 Wkr^T, 1600-1663 zero
  u16* WuqrT  = (u16*)alloc((size_t)3072 * CQ_ * 2);
  u16* WukvT  = (u16*)alloc((size_t)4096 * CKV_ * 2);
  u16* WoT   = (u16*)alloc((size_t)H_ * H_ * 2);
  u16* w13T  = (u16*)alloc((size_t)E_ * 2048 * H_ * 2);
  u16* w2T   = (u16*)alloc((size_t)E_ * H_ * I_ * 2);
  u16* w13sT = (u16*)alloc((size_t)NS_ * 2048 * H_ * 2);
  u16* w2sT  = (u16*)alloc((size_t)NS_ * H_ * I_ * 2);
  float* x1  = (float*)alloc((size_t)T_ * H_ * 4);
  u16* h2b   = (u16*)alloc((size_t)T_ * H_ * 2);
  int* meta  = (int*)alloc(64 * 4);
  int* eidx  = (int*)alloc((size_t)T_ * 2 * 4);
  float* ew  = (float*)alloc((size_t)T_ * 2 * 4);
  int* rowlist = (int*)alloc(8192 * 4);
  float* roww  = (float*)alloc(8192 * 4);
  int* slotidx = (int*)alloc((size_t)T_ * 2 * 4);

  // ---- phase-overlapped region ----
  char* mark = p;
  u16* hn    = (u16*)alloc((size_t)T_ * H_ * 2);
  float* tq  = (float*)alloc((size_t)T_ * CQ_ * 4);
  u16* cq    = (u16*)alloc((size_t)T_ * CQ_ * 2);
  u16* qbuf  = (u16*)alloc((size_t)T_ * H_ * 2);
  u16* qrb   = (u16*)alloc((size_t)T_ * NH_ * R_ * 2);
  float* tkv = (float*)alloc((size_t)T_ * CKV_ * 4);
  u16* ckv   = (u16*)alloc((size_t)T_ * CKV_ * 2);
  u16* kbuf  = (u16*)alloc((size_t)T_ * H_ * 2);
  u16* vbuf  = (u16*)alloc((size_t)T_ * H_ * 2);
  float* krb = (float*)alloc((size_t)T_ * R_ * 4);
  u16* qcat  = (u16*)alloc((size_t)B_ * NH_ * S_ * DQK_ * 2);
  u16* kcat  = (u16*)alloc((size_t)B_ * NH_ * S_ * DQK_ * 2);
  u16* vT    = (u16*)alloc((size_t)B_ * NH_ * DH_ * S_ * 2);
  u16* aout  = (u16*)alloc((size_t)T_ * H_ * 2);

  p = mark;
  u16* ub  = (u16*)alloc((size_t)8192 * I_ * 2);
  u16* o2  = (u16*)alloc((size_t)8192 * H_ * 2);

  dim3 b256(256), b64(64), b512(512);

  hipMemsetAsync(meta, 0, 64 * 4, stream);
  hipMemsetAsync(WdqkvT + (size_t)1600 * H_, 0, (size_t)64 * H_ * 2, stream);

  rope_table_kernel<<<dim3((S_ * 32 + 255) / 256), b256, 0, stream>>>(cosT, sinT);

  ttc_kernel<<<dim3(CQ_ / 64, H_ / 64, 1),  b256, 0, stream>>>(Wdq,  WdqkvT, H_,  CQ_, 0, 0, 1);
  ttc_kernel<<<dim3(CKV_ / 64, H_ / 64, 1), b256, 0, stream>>>(Wdkv, WdqkvT, H_,  CKV_, 0, 1024, 1);
  ttc_kernel<<<dim3(1, H_ / 64, 1),         b256, 0, stream>>>(Wkr,  WdqkvT, H_,  R_, 0, 1536, 1);
  ttc_kernel<<<dim3(H_ / 64, CQ_ / 64, 1),  b256, 0, stream>>>(Wuq,  WuqrT,  CQ_, H_, 0, 0, 1);
  ttc_kernel<<<dim3(1024 / 64, CQ_ / 64, 1), b256, 0, stream>>>(Wqr, WuqrT,  CQ_, 1024, 0, 2048, 1);
  ttc_kernel<<<dim3(H_ / 64, CKV_ / 64, 1), b256, 0, stream>>>(Wuk,  WukvT,  CKV_, H_, 0, 0, 1);
  ttc_kernel<<<dim3(H_ / 64, CKV_ / 64, 1), b256, 0, stream>>>(Wuv,  WukvT,  CKV_, H_, 0, 2048, 1);
  ttc_kernel<<<dim3(H_ / 64, H_ / 64, 1),   b256, 0, stream>>>(Wo,   WoT,    H_,  H_, 0, 0, 1);
  ttc_kernel<<<dim3(I_ / 64, H_ / 64, E_),  b256, 0, stream>>>(w1,  w13T, H_, I_, (size_t)2048 * H_, 0, 2);
  ttc_kernel<<<dim3(I_ / 64, H_ / 64, E_),  b256, 0, stream>>>(w3,  w13T, H_, I_, (size_t)2048 * H_, 1, 2);
  ttc_kernel<<<dim3(H_ / 64, I_ / 64, E_),  b256, 0, stream>>>(w2,  w2T,  I_, H_, (size_t)H_ * I_, 0, 1);
  ttc_kernel<<<dim3(I_ / 64, H_ / 64, NS_), b256, 0, stream>>>(w1s, w13sT, H_, I_, (size_t)2048 * H_, 0, 2);
  ttc_kernel<<<dim3(I_ / 64, H_ / 64, NS_), b256, 0, stream>>>(w3s, w13sT, H_, I_, (size_t)2048 * H_, 1, 2);
  ttc_kernel<<<dim3(H_ / 64, I_ / 64, NS_), b256, 0, stream>>>(w2s, w2sT, I_, H_, (size_t)H_ * I_, 0, 1);

  rmsnorm_kernel<<<T_, b256, 0, stream>>>(x, anw, hn, nullptr, H_);

  // fused dq+dkv+kr: N=1664, splits 1024/1536 -> tq, tkv, krb(raw)
  gemm_kernel64<5><<<dim3(1664 / 128, T_ / 64), b256, 0, stream>>>(hn, H_, WdqkvT, H_, T_,
      tq, tkv, krb, nullptr, nullptr, CQ_, CKV_, 1024, 1536, nullptr);
  rmsnorm_kernel<<<T_, b256, 0, stream>>>(tq, qnw, cq, nullptr, CQ_);
  rmsnorm_kernel<<<T_, b256, 0, stream>>>(tkv, kvnw, ckv, nullptr, CKV_);
  gemm_kernel64<4><<<dim3(3072 / 128, T_ / 64), b256, 0, stream>>>(cq, CQ_, WuqrT, CQ_, T_,
      nullptr, nullptr, nullptr, qbuf, qrb, H_, NH_ * R_, 2048, 0, nullptr);
  gemm_kernel64<4><<<dim3(4096 / 128, T_ / 64), b256, 0, stream>>>(ckv, CKV_, WukvT, CKV_, T_,
      nullptr, nullptr, nullptr, kbuf, vbuf, H_, H_, 2048, 0, nullptr);

  size_t qct = (size_t)B_ * NH_ * S_ * DQK_;
  build_qkcat_kernel<<<dim3((qct / 8 + 255) / 256, 2), b256, 0, stream>>>(qbuf, qrb, kbuf, krb, cosT, sinT, qcat, kcat);
  build_vT_kernel<<<dim3(S_ / 32, DH_ / 32, B_ * NH_), b256, 0, stream>>>(vbuf, vT);

  attn_kernel<<<dim3(S_ / 64, NH_, B_), b256, 0, stream>>>(qcat, kcat, vT, aout);

  gemm_kernel64<2><<<dim3(H_ / 128, T_ / 64), b256, 0, stream>>>(aout, H_, WoT, H_, T_,
      x1, nullptr, nullptr, nullptr, nullptr, H_, 0, 0, 0, x);

  rmsnorm_route_kernel<<<T_, b256, 0, stream>>>(x1, fnw, cent, ebias, h2b, eidx, ew, meta);
  scan_kernel<<<dim3(1), b64, 0, stream>>>(meta);
  fill_kernel<<<dim3((T_ + 255) / 256), b256, 0, stream>>>(eidx, ew, meta, rowlist, roww, slotidx);

  moe_gemm13_kernel<<<dim3(2048 / 128, 16, 10), b512, 0, stream>>>(h2b, w13T, w13sT,
      rowlist, meta + 16, meta + 32, roww, ub);
  moe_gemm2_kernel<<<dim3(H_ / 128, 16, 10), b512, 0, stream>>>(ub, w2T, w2sT,
      meta + 16, meta + 32, o2);

  combine_kernel<<<T_, b256, 0, stream>>>(x1, o2, slotidx, out);
}